// Round 5
// baseline (705.050 us; speedup 1.0000x reference)
//
#include <hip/hip_runtime.h>
#include <math.h>

#define NB   8
#define NPTS 1024
#define PTS  8192      // NB*NPTS
#define KNN  16
#define PK   (PTS*KNN) // 131072

typedef __attribute__((ext_vector_type(8))) _Float16 f16x8;
typedef __attribute__((ext_vector_type(4))) float f32x4;

__device__ __forceinline__ unsigned short f2h(float f) {
  _Float16 h = (_Float16)f;
  union { _Float16 h; unsigned short u; } c; c.h = h;
  return c.u;
}

// ---------------- kNN: one WAVE per point; register-resident top-16, barrier-free ----------------
__global__ __launch_bounds__(256) void knn_kernel(const float* __restrict__ pos,
                                                  int* __restrict__ idx,
                                                  float* __restrict__ rel) {
  __shared__ float px[NPTS], py[NPTS], pz[NPTS];
  const int t = threadIdx.x;
  const int wv = t >> 6, lane = t & 63;
  const int b = blockIdx.x;
  const int graph = b >> 8;             // 256 blocks per graph
  const int base = graph << 10;
  for (int j = t; j < NPTS; j += 256) {
    px[j] = pos[3*(base+j)];
    py[j] = pos[3*(base+j)+1];
    pz[j] = pos[3*(base+j)+2];
  }
  __syncthreads();

  const int il = ((b & 255) << 2) + wv; // point index within graph
  const float pix = px[il], piy = py[il], piz = pz[il];
  const float sqi = pix*pix + piy*piy + piz*piz;

  float d[16];
  #pragma unroll
  for (int q = 0; q < 16; ++q) {
    const int j = (q << 6) + lane;
    const float x = px[j], y = py[j], z = pz[j];
    const float sqj = x*x + y*y + z*z;
    const float dt  = pix*x + piy*y + piz*z;
    d[q] = sqi + sqj - 2.0f*dt;
  }
  float mv = d[0]; int mq = 0;
  #pragma unroll
  for (int q = 1; q < 16; ++q) { if (d[q] < mv) { mv = d[q]; mq = q; } }

  int sel = 0;
  for (int s = 0; s < KNN; ++s) {
    float v = mv; int j = (mq << 6) + lane;
    #pragma unroll
    for (int m = 1; m <= 32; m <<= 1) {
      const float v2 = __shfl_xor(v, m);
      const int   j2 = __shfl_xor(j, m);
      if (v2 < v || (v2 == v && j2 < j)) { v = v2; j = j2; }
    }
    if (lane == s) sel = j;
    if (lane == (j & 63)) {
      const int wq = j >> 6;
      #pragma unroll
      for (int q = 0; q < 16; ++q) if (q == wq) d[q] = INFINITY;
      mv = d[0]; mq = 0;
      #pragma unroll
      for (int q = 1; q < 16; ++q) { if (d[q] < mv) { mv = d[q]; mq = q; } }
    }
  }

  if (lane < KNN) {
    const int i = base + il;
    const int r = i*KNN + lane;
    idx[r] = base + sel;
    rel[3*r]   = px[sel] - pix;
    rel[3*r+1] = py[sel] - piy;
    rel[3*r+2] = pz[sel] - piz;
  }
}

// ---------------- conv1 layer1 ----------------
__global__ __launch_bounds__(256) void conv1_l1_kernel(const float* __restrict__ pos,
    const int* __restrict__ idx, const float* __restrict__ rel,
    const float* __restrict__ W1, const float* __restrict__ b1,
    float* __restrict__ z1) {
  const int r0 = blockIdx.x * 64;
  const int t = threadIdx.x;
  __shared__ float f[64][6];
  if (t < 64) {
    const int r = r0 + t;
    const int j = idx[r];
    f[t][0] = pos[3*j]; f[t][1] = pos[3*j+1]; f[t][2] = pos[3*j+2];
    f[t][3] = rel[3*r]; f[t][4] = rel[3*r+1]; f[t][5] = rel[3*r+2];
  }
  __syncthreads();
  const int c = t & 63, rg = t >> 6;
  float w[6];
  #pragma unroll
  for (int q = 0; q < 6; ++q) w[q] = W1[q*64 + c];
  const float bb = b1[c];
  for (int j = 0; j < 16; ++j) {
    const int lr = rg + 4*j;
    float z = bb;
    #pragma unroll
    for (int q = 0; q < 6; ++q) z += f[lr][q]*w[q];
    z1[(size_t)(r0+lr)*64 + c] = z;
  }
}

// ---------------- BN stats ----------------
__global__ __launch_bounds__(256) void stats_partial_kernel(const float* __restrict__ z,
    int rowsPerBlock, int C, float* __restrict__ partial) {
  const int t = threadIdx.x;
  const int c = t & (C-1);
  const int rl = t / C;
  const int RL = 256 / C;
  const int r0 = blockIdx.x * rowsPerBlock;
  float s = 0.0f, s2 = 0.0f;
  for (int r = rl; r < rowsPerBlock; r += RL) {
    const float v = z[(size_t)(r0 + r)*C + c];
    s += v; s2 += v*v;
  }
  __shared__ float ls[256], ls2[256];
  ls[t] = s; ls2[t] = s2;
  __syncthreads();
  if (t < C) {
    float a = ls[t], a2 = ls2[t];
    for (int q = 1; q < RL; ++q) { a += ls[t + q*C]; a2 += ls2[t + q*C]; }
    partial[blockIdx.x*2*C + t]     = a;
    partial[blockIdx.x*2*C + C + t] = a2;
  }
}

__global__ __launch_bounds__(256) void stats_final_kernel(const float* __restrict__ partial,
    int G, int C, float invRows,
    const float* __restrict__ gamma, const float* __restrict__ beta,
    float* __restrict__ ss) {
  const int t = threadIdx.x;
  if (t >= C) return;
  float s = 0.0f, s2 = 0.0f;
  for (int g = 0; g < G; ++g) { s += partial[g*2*C + t]; s2 += partial[g*2*C + C + t]; }
  const float mu  = s * invRows;
  const float var = s2 * invRows - mu*mu;
  const float sc  = gamma[t] * rsqrtf(var + 1e-5f);
  ss[t] = sc; ss[C + t] = beta[t] - mu*sc;
}

// ---------------- conv1 layer2 + max ----------------
__global__ __launch_bounds__(64) void conv1_l2max_kernel(const float* __restrict__ z1,
    const float* __restrict__ ss, const float* __restrict__ W2,
    const float* __restrict__ b2, float* __restrict__ x1) {
  const int i = blockIdx.x;
  const int t = threadIdx.x;
  __shared__ float h[KNN][64];
  const float sc = ss[t], sh = ss[64+t];
  #pragma unroll
  for (int k = 0; k < KNN; ++k) {
    const float z = z1[(size_t)(i*KNN+k)*64 + t];
    h[k][t] = fmaxf(z*sc + sh, 0.0f);
  }
  __syncthreads();
  float w[64];
  #pragma unroll
  for (int d = 0; d < 64; ++d) w[d] = W2[d*64 + t];
  const float bb = b2[t];
  float acc = -INFINITY;
  for (int k = 0; k < KNN; ++k) {
    float y = bb;
    #pragma unroll
    for (int d = 0; d < 64; ++d) y += h[k][d]*w[d];
    acc = fmaxf(acc, y);
  }
  x1[(size_t)i*64 + t] = acc;
}

// ---------------- conv2 layer1 ----------------
__global__ __launch_bounds__(256) void conv2_l1_kernel(const float* __restrict__ x1,
    const int* __restrict__ idx, const float* __restrict__ rel,
    const float* __restrict__ W, const float* __restrict__ bias,
    float* __restrict__ za) {
  const int i = blockIdx.x;
  const int t = threadIdx.x;
  const int c = t & 63, kg = t >> 6;
  __shared__ float xg[KNN][64];
  __shared__ float rl[KNN][3];
  #pragma unroll
  for (int j = 0; j < 4; ++j) {
    const int k = kg + 4*j;
    const int gj = idx[i*KNN + k];
    xg[k][c] = x1[(size_t)gj*64 + c];
  }
  if (t < KNN*3) rl[t/3][t%3] = rel[i*KNN*3 + t];
  __syncthreads();
  float w[67];
  #pragma unroll
  for (int q = 0; q < 67; ++q) w[q] = W[q*64 + c];
  const float bb = bias[c];
  #pragma unroll
  for (int j = 0; j < 4; ++j) {
    const int k = kg + 4*j;
    float y = bb + rl[k][0]*w[64] + rl[k][1]*w[65] + rl[k][2]*w[66];
    #pragma unroll
    for (int q = 0; q < 64; ++q) y += xg[k][q]*w[q];
    za[(size_t)(i*KNN+k)*64 + c] = y;
  }
}

// ---------------- conv2 layer2 ----------------
__global__ __launch_bounds__(256) void conv2_l2_kernel(const float* __restrict__ za,
    const float* __restrict__ ss, const float* __restrict__ W2,
    const float* __restrict__ b2, float* __restrict__ zb) {
  const int r0 = blockIdx.x * 128;
  const int t = threadIdx.x;
  const int c = t & 127, rg = t >> 7;
  __shared__ float h[128][64];
  for (int q = t; q < 128*64; q += 256) {
    const int lr = q >> 6, f = q & 63;
    const float z = za[(size_t)(r0+lr)*64 + f];
    h[lr][f] = fmaxf(z*ss[f] + ss[64+f], 0.0f);
  }
  __syncthreads();
  float w[64];
  #pragma unroll
  for (int q = 0; q < 64; ++q) w[q] = W2[q*128 + c];
  const float bb = b2[c];
  for (int j = 0; j < 64; ++j) {
    const int lr = rg + 2*j;
    float y = bb;
    #pragma unroll
    for (int q = 0; q < 64; ++q) y += h[lr][q]*w[q];
    zb[(size_t)(r0+lr)*128 + c] = y;
  }
}

// ---------------- W3 -> fp16 transposed [1024][128] ----------------
__global__ __launch_bounds__(256) void w3t_kernel(const float* __restrict__ W3,
                                                  unsigned short* __restrict__ W3T) {
  const int k = blockIdx.x;           // 0..127
  for (int n = threadIdx.x; n < 1024; n += 256)
    W3T[n*128 + k] = f2h(W3[(size_t)k*1024 + n]);
}

// ---------------- conv2 layer3 + max: fp16 MFMA, A in LDS (1 barrier), B direct from L2 ----------------
// grid: 1024 blocks of 128 rows; loop 8 col-chunks of 128. No per-chunk barriers:
// B fragments are coalesced 16B global loads from W3T (256KB, L2-hot).
__global__ __launch_bounds__(256) void conv2_l3max_mfma(
    const float* __restrict__ zb, const float* __restrict__ ss,
    const unsigned short* __restrict__ W3T, const float* __restrict__ b3,
    float* __restrict__ x2) {
  __shared__ unsigned short As[128*128];
  const int r0 = blockIdx.x * 128;
  const int t = threadIdx.x;
  const int lane = t & 63, w = t >> 6;
  const int quad = lane >> 4, mcol = lane & 15;

  // ---- stage A: relu(bn(zb)) -> fp16, swizzled ----
  {
    const int kb = t & 15;          // 16B block along K (8 halves)
    const int rr = t >> 4;          // 16 rows per pass
    float sc[8], sh[8];
    #pragma unroll
    for (int q = 0; q < 8; ++q) { sc[q] = ss[kb*8 + q]; sh[q] = ss[128 + kb*8 + q]; }
    #pragma unroll
    for (int it = 0; it < 8; ++it) {
      const int r = rr + it*16;
      const float* src = zb + (size_t)(r0 + r)*128 + kb*8;
      const float4 v0 = *(const float4*)(src);
      const float4 v1 = *(const float4*)(src + 4);
      union { unsigned short s[8]; uint4 v; } o;
      o.s[0] = f2h(fmaxf(v0.x*sc[0] + sh[0], 0.0f));
      o.s[1] = f2h(fmaxf(v0.y*sc[1] + sh[1], 0.0f));
      o.s[2] = f2h(fmaxf(v0.z*sc[2] + sh[2], 0.0f));
      o.s[3] = f2h(fmaxf(v0.w*sc[3] + sh[3], 0.0f));
      o.s[4] = f2h(fmaxf(v1.x*sc[4] + sh[4], 0.0f));
      o.s[5] = f2h(fmaxf(v1.y*sc[5] + sh[5], 0.0f));
      o.s[6] = f2h(fmaxf(v1.z*sc[6] + sh[6], 0.0f));
      o.s[7] = f2h(fmaxf(v1.w*sc[7] + sh[7], 0.0f));
      *(uint4*)(As + r*128 + ((kb ^ (r & 7)) * 8)) = o.v;
    }
  }
  __syncthreads();   // the only barrier

  const int wrow = (w >> 1) * 64;
  const int wcol = (w & 1) * 64;

  for (int chunk = 0; chunk < 8; ++chunk) {
    const int n0 = chunk * 128;

    f32x4 acc[4][4];
    #pragma unroll
    for (int mi = 0; mi < 4; ++mi)
      #pragma unroll
      for (int ni = 0; ni < 4; ++ni)
        acc[mi][ni] = (f32x4){0.f, 0.f, 0.f, 0.f};

    #pragma unroll
    for (int ks = 0; ks < 4; ++ks) {
      f16x8 af[4], bfr[4];
      #pragma unroll
      for (int ni = 0; ni < 4; ++ni) {
        const int nr = n0 + wcol + ni*16 + mcol;        // global W3T row
        bfr[ni] = *(const f16x8*)(W3T + (size_t)nr*128 + ks*32 + quad*8);
      }
      #pragma unroll
      for (int mi = 0; mi < 4; ++mi) {
        const int row = wrow + mi*16 + mcol;
        af[mi] = *(const f16x8*)(As + row*128 + (((ks*4 + quad) ^ (row & 7)) * 8));
      }
      #pragma unroll
      for (int mi = 0; mi < 4; ++mi)
        #pragma unroll
        for (int ni = 0; ni < 4; ++ni)
          acc[mi][ni] = __builtin_amdgcn_mfma_f32_16x16x32_f16(af[mi], bfr[ni], acc[mi][ni], 0, 0, 0);
    }

    // ---- fused max over the 16 rows of each tile (= one point) ----
    #pragma unroll
    for (int mi = 0; mi < 4; ++mi) {
      const int p = blockIdx.x*8 + (w >> 1)*4 + mi;
      #pragma unroll
      for (int ni = 0; ni < 4; ++ni) {
        f32x4 a = acc[mi][ni];
        float m = fmaxf(fmaxf(a[0], a[1]), fmaxf(a[2], a[3]));
        m = fmaxf(m, __shfl_xor(m, 16));
        m = fmaxf(m, __shfl_xor(m, 32));
        if (quad == 0) {
          const int n = n0 + wcol + ni*16 + mcol;
          x2[(size_t)p*1024 + n] = m + b3[n];
        }
      }
    }
  }
}

// ---------------- global max pool, two coalesced stages ----------------
__global__ __launch_bounds__(256) void pool1_kernel(const float* __restrict__ x2,
                                                    float* __restrict__ pmax) {
  const int b = blockIdx.x >> 4, g = blockIdx.x & 15;
  const int t = threadIdx.x;
  const float* base = x2 + (size_t)(b*1024 + g*64)*1024;
  float m0 = -INFINITY, m1 = -INFINITY, m2 = -INFINITY, m3 = -INFINITY;
  for (int n = 0; n < 64; ++n) {
    const float* row = base + (size_t)n*1024;
    m0 = fmaxf(m0, row[t]);
    m1 = fmaxf(m1, row[t + 256]);
    m2 = fmaxf(m2, row[t + 512]);
    m3 = fmaxf(m3, row[t + 768]);
  }
  float* o = pmax + (size_t)blockIdx.x*1024;
  o[t] = m0; o[t+256] = m1; o[t+512] = m2; o[t+768] = m3;
}

__global__ __launch_bounds__(256) void pool2_kernel(const float* __restrict__ pmax,
                                                    float* __restrict__ g) {
  const int id = blockIdx.x*256 + threadIdx.x; // b*1024 + c
  const int b = id >> 10, c = id & 1023;
  float m = -INFINITY;
  for (int q = 0; q < 16; ++q) m = fmaxf(m, pmax[(size_t)(b*16 + q)*1024 + c]);
  g[id] = m;
}

// ---------------- final linear (partials over c-quarters) ----------------
__global__ __launch_bounds__(256) void lin_kernel(const float* __restrict__ g,
    const float* __restrict__ W, float* __restrict__ zpart) {
  const int b = blockIdx.x >> 2, q = blockIdx.x & 3;
  const int o = threadIdx.x;
  const float* gb = g + b*1024 + q*256;
  const float* Wq = W + q*256*256;
  float acc = 0.0f;
  for (int c = 0; c < 256; ++c) acc += gb[c] * Wq[c*256 + o];
  zpart[blockIdx.x*256 + o] = acc;
}

// ---------------- final BN(8 rows) + relu ----------------
__global__ __launch_bounds__(256) void final_kernel(const float* __restrict__ zpart,
    const float* __restrict__ lb, const float* __restrict__ lg,
    const float* __restrict__ lbe, float* __restrict__ out) {
  const int o = threadIdx.x;
  float z[NB]; float s = 0.0f, s2 = 0.0f;
  #pragma unroll
  for (int b = 0; b < NB; ++b) {
    float v = lb[o];
    #pragma unroll
    for (int q = 0; q < 4; ++q) v += zpart[(b*4+q)*256 + o];
    z[b] = v; s += v; s2 += v*v;
  }
  const float mu  = s * 0.125f;
  const float var = s2 * 0.125f - mu*mu;
  const float inv = rsqrtf(var + 1e-5f);
  const float sc = lg[o]*inv, sh = lbe[o] - mu*sc;
  #pragma unroll
  for (int b = 0; b < NB; ++b) out[b*256 + o] = fmaxf(z[b]*sc + sh, 0.0f);
}

extern "C" void kernel_launch(void* const* d_in, const int* in_sizes, int n_in,
                              void* d_out, int out_size, void* d_ws, size_t ws_size,
                              hipStream_t stream) {
  const float* pos    = (const float*)d_in[0];
  const float* c1_W1  = (const float*)d_in[2];
  const float* c1_b1  = (const float*)d_in[3];
  const float* c1_g1  = (const float*)d_in[4];
  const float* c1_be1 = (const float*)d_in[5];
  const float* c1_W2  = (const float*)d_in[6];
  const float* c1_b2  = (const float*)d_in[7];
  const float* c2_W1  = (const float*)d_in[8];
  const float* c2_b1  = (const float*)d_in[9];
  const float* c2_g1  = (const float*)d_in[10];
  const float* c2_be1 = (const float*)d_in[11];
  const float* c2_W2  = (const float*)d_in[12];
  const float* c2_b2  = (const float*)d_in[13];
  const float* c2_g2  = (const float*)d_in[14];
  const float* c2_be2 = (const float*)d_in[15];
  const float* c2_W3  = (const float*)d_in[16];
  const float* c2_b3  = (const float*)d_in[17];
  const float* lin_W  = (const float*)d_in[18];
  const float* lin_b  = (const float*)d_in[19];
  const float* lin_g  = (const float*)d_in[20];
  const float* lin_be = (const float*)d_in[21];
  float* out = (float*)d_out;

  char* ws = (char*)d_ws;
  int*   idx     = (int*)  (ws + 0);
  float* rel     = (float*)(ws + 524288);
  float* ss1     = (float*)(ws + 2097152);           // 128
  float* ssA     = (float*)(ws + 2097152 + 512);     // 128
  float* ssB     = (float*)(ws + 2097152 + 1024);    // 256
  float* zpart   = (float*)(ws + 2097152 + 2048);    // 8192
  float* gpool   = (float*)(ws + 2097152 + 2048 + 32768);          // 8192
  float* partial = (float*)(ws + 2097152 + 2048 + 65536);          // 65536 floats
  float* bufA    = (float*)(ws + 2426880);           // 33554432 B (z1 / za / x2)
  float* x1      = (float*)(ws + 35981312);          // 2097152 B (x1, then W3T)
  unsigned short* W3T = (unsigned short*)(ws + 35981312);
  float* zb      = (float*)(ws + 38078464);          // 67108864 B (zb, then pmax)
  float* pmax    = (float*)(ws + 38078464);

  const float invPK = 1.0f / (float)PK;

  knn_kernel<<<PTS/4, 256, 0, stream>>>(pos, idx, rel);
  conv1_l1_kernel<<<PK/64, 256, 0, stream>>>(pos, idx, rel, c1_W1, c1_b1, bufA);
  stats_partial_kernel<<<256, 256, 0, stream>>>(bufA, PK/256, 64, partial);
  stats_final_kernel<<<1, 256, 0, stream>>>(partial, 256, 64, invPK, c1_g1, c1_be1, ss1);
  conv1_l2max_kernel<<<PTS, 64, 0, stream>>>(bufA, ss1, c1_W2, c1_b2, x1);
  conv2_l1_kernel<<<PTS, 256, 0, stream>>>(x1, idx, rel, c2_W1, c2_b1, bufA);
  w3t_kernel<<<128, 256, 0, stream>>>(c2_W3, W3T);
  stats_partial_kernel<<<256, 256, 0, stream>>>(bufA, PK/256, 64, partial);
  stats_final_kernel<<<1, 256, 0, stream>>>(partial, 256, 64, invPK, c2_g1, c2_be1, ssA);
  conv2_l2_kernel<<<PK/128, 256, 0, stream>>>(bufA, ssA, c2_W2, c2_b2, zb);
  stats_partial_kernel<<<256, 256, 0, stream>>>(zb, PK/256, 128, partial);
  stats_final_kernel<<<1, 256, 0, stream>>>(partial, 256, 128, invPK, c2_g2, c2_be2, ssB);
  conv2_l3max_mfma<<<PK/128, 256, 0, stream>>>(zb, ssB, W3T, c2_b3, bufA);
  pool1_kernel<<<NB*16, 256, 0, stream>>>(bufA, pmax);
  pool2_kernel<<<PTS/256, 256, 0, stream>>>(pmax, gpool);
  lin_kernel<<<32, 256, 0, stream>>>(gpool, lin_W, zpart);
  final_kernel<<<1, 256, 0, stream>>>(zpart, lin_b, lin_g, lin_be, out);
}

// Round 7
// 645.655 us; speedup vs baseline: 1.0920x; 1.0920x over previous
//
#include <hip/hip_runtime.h>
#include <math.h>

#define NB   8
#define NPTS 1024
#define PTS  8192      // NB*NPTS
#define KNN  16
#define PK   (PTS*KNN) // 131072

typedef __attribute__((ext_vector_type(8))) _Float16 f16x8;
typedef __attribute__((ext_vector_type(4))) float f32x4;

__device__ __forceinline__ unsigned short f2h(float f) {
  _Float16 h = (_Float16)f;
  union { _Float16 h; unsigned short u; } c; c.h = h;
  return c.u;
}

// ---------------- kNN: one WAVE per point; register-resident top-16, barrier-free ----------------
__global__ __launch_bounds__(256) void knn_kernel(const float* __restrict__ pos,
                                                  int* __restrict__ idx,
                                                  float* __restrict__ rel) {
  __shared__ float px[NPTS], py[NPTS], pz[NPTS];
  const int t = threadIdx.x;
  const int wv = t >> 6, lane = t & 63;
  const int b = blockIdx.x;
  const int graph = b >> 8;             // 256 blocks per graph
  const int base = graph << 10;
  for (int j = t; j < NPTS; j += 256) {
    px[j] = pos[3*(base+j)];
    py[j] = pos[3*(base+j)+1];
    pz[j] = pos[3*(base+j)+2];
  }
  __syncthreads();

  const int il = ((b & 255) << 2) + wv; // point index within graph
  const float pix = px[il], piy = py[il], piz = pz[il];
  const float sqi = pix*pix + piy*piy + piz*piz;

  float d[16];
  #pragma unroll
  for (int q = 0; q < 16; ++q) {
    const int j = (q << 6) + lane;
    const float x = px[j], y = py[j], z = pz[j];
    const float sqj = x*x + y*y + z*z;
    const float dt  = pix*x + piy*y + piz*z;
    d[q] = sqi + sqj - 2.0f*dt;
  }
  float mv = d[0]; int mq = 0;
  #pragma unroll
  for (int q = 1; q < 16; ++q) { if (d[q] < mv) { mv = d[q]; mq = q; } }

  int sel = 0;
  for (int s = 0; s < KNN; ++s) {
    float v = mv; int j = (mq << 6) + lane;
    #pragma unroll
    for (int m = 1; m <= 32; m <<= 1) {
      const float v2 = __shfl_xor(v, m);
      const int   j2 = __shfl_xor(j, m);
      if (v2 < v || (v2 == v && j2 < j)) { v = v2; j = j2; }
    }
    if (lane == s) sel = j;
    if (lane == (j & 63)) {
      const int wq = j >> 6;
      #pragma unroll
      for (int q = 0; q < 16; ++q) if (q == wq) d[q] = INFINITY;
      mv = d[0]; mq = 0;
      #pragma unroll
      for (int q = 1; q < 16; ++q) { if (d[q] < mv) { mv = d[q]; mq = q; } }
    }
  }

  if (lane < KNN) {
    const int i = base + il;
    const int r = i*KNN + lane;
    idx[r] = base + sel;
    rel[3*r]   = px[sel] - pix;
    rel[3*r+1] = py[sel] - piy;
    rel[3*r+2] = pz[sel] - piz;
  }
}

// ---------------- conv1 layer1 ----------------
__global__ __launch_bounds__(256) void conv1_l1_kernel(const float* __restrict__ pos,
    const int* __restrict__ idx, const float* __restrict__ rel,
    const float* __restrict__ W1, const float* __restrict__ b1,
    float* __restrict__ z1) {
  const int r0 = blockIdx.x * 64;
  const int t = threadIdx.x;
  __shared__ float f[64][6];
  if (t < 64) {
    const int r = r0 + t;
    const int j = idx[r];
    f[t][0] = pos[3*j]; f[t][1] = pos[3*j+1]; f[t][2] = pos[3*j+2];
    f[t][3] = rel[3*r]; f[t][4] = rel[3*r+1]; f[t][5] = rel[3*r+2];
  }
  __syncthreads();
  const int c = t & 63, rg = t >> 6;
  float w[6];
  #pragma unroll
  for (int q = 0; q < 6; ++q) w[q] = W1[q*64 + c];
  const float bb = b1[c];
  for (int j = 0; j < 16; ++j) {
    const int lr = rg + 4*j;
    float z = bb;
    #pragma unroll
    for (int q = 0; q < 6; ++q) z += f[lr][q]*w[q];
    z1[(size_t)(r0+lr)*64 + c] = z;
  }
}

// ---------------- BN stats ----------------
__global__ __launch_bounds__(256) void stats_partial_kernel(const float* __restrict__ z,
    int rowsPerBlock, int C, float* __restrict__ partial) {
  const int t = threadIdx.x;
  const int c = t & (C-1);
  const int rl = t / C;
  const int RL = 256 / C;
  const int r0 = blockIdx.x * rowsPerBlock;
  float s = 0.0f, s2 = 0.0f;
  for (int r = rl; r < rowsPerBlock; r += RL) {
    const float v = z[(size_t)(r0 + r)*C + c];
    s += v; s2 += v*v;
  }
  __shared__ float ls[256], ls2[256];
  ls[t] = s; ls2[t] = s2;
  __syncthreads();
  if (t < C) {
    float a = ls[t], a2 = ls2[t];
    for (int q = 1; q < RL; ++q) { a += ls[t + q*C]; a2 += ls2[t + q*C]; }
    partial[blockIdx.x*2*C + t]     = a;
    partial[blockIdx.x*2*C + C + t] = a2;
  }
}

__global__ __launch_bounds__(256) void stats_final_kernel(const float* __restrict__ partial,
    int G, int C, float invRows,
    const float* __restrict__ gamma, const float* __restrict__ beta,
    float* __restrict__ ss) {
  const int t = threadIdx.x;
  if (t >= C) return;
  float s = 0.0f, s2 = 0.0f;
  for (int g = 0; g < G; ++g) { s += partial[g*2*C + t]; s2 += partial[g*2*C + C + t]; }
  const float mu  = s * invRows;
  const float var = s2 * invRows - mu*mu;
  const float sc  = gamma[t] * rsqrtf(var + 1e-5f);
  ss[t] = sc; ss[C + t] = beta[t] - mu*sc;
}

// ---------------- conv1 layer2 + max ----------------
__global__ __launch_bounds__(64) void conv1_l2max_kernel(const float* __restrict__ z1,
    const float* __restrict__ ss, const float* __restrict__ W2,
    const float* __restrict__ b2, float* __restrict__ x1) {
  const int i = blockIdx.x;
  const int t = threadIdx.x;
  __shared__ float h[KNN][64];
  const float sc = ss[t], sh = ss[64+t];
  #pragma unroll
  for (int k = 0; k < KNN; ++k) {
    const float z = z1[(size_t)(i*KNN+k)*64 + t];
    h[k][t] = fmaxf(z*sc + sh, 0.0f);
  }
  __syncthreads();
  float w[64];
  #pragma unroll
  for (int d = 0; d < 64; ++d) w[d] = W2[d*64 + t];
  const float bb = b2[t];
  float acc = -INFINITY;
  for (int k = 0; k < KNN; ++k) {
    float y = bb;
    #pragma unroll
    for (int d = 0; d < 64; ++d) y += h[k][d]*w[d];
    acc = fmaxf(acc, y);
  }
  x1[(size_t)i*64 + t] = acc;
}

// ---------------- conv2 layer1 ----------------
__global__ __launch_bounds__(256) void conv2_l1_kernel(const float* __restrict__ x1,
    const int* __restrict__ idx, const float* __restrict__ rel,
    const float* __restrict__ W, const float* __restrict__ bias,
    float* __restrict__ za) {
  const int i = blockIdx.x;
  const int t = threadIdx.x;
  const int c = t & 63, kg = t >> 6;
  __shared__ float xg[KNN][64];
  __shared__ float rl[KNN][3];
  #pragma unroll
  for (int j = 0; j < 4; ++j) {
    const int k = kg + 4*j;
    const int gj = idx[i*KNN + k];
    xg[k][c] = x1[(size_t)gj*64 + c];
  }
  if (t < KNN*3) rl[t/3][t%3] = rel[i*KNN*3 + t];
  __syncthreads();
  float w[67];
  #pragma unroll
  for (int q = 0; q < 67; ++q) w[q] = W[q*64 + c];
  const float bb = bias[c];
  #pragma unroll
  for (int j = 0; j < 4; ++j) {
    const int k = kg + 4*j;
    float y = bb + rl[k][0]*w[64] + rl[k][1]*w[65] + rl[k][2]*w[66];
    #pragma unroll
    for (int q = 0; q < 64; ++q) y += xg[k][q]*w[q];
    za[(size_t)(i*KNN+k)*64 + c] = y;
  }
}

// ---------------- W3 -> fp16 transposed [1024][128] ----------------
__global__ __launch_bounds__(256) void w3t_kernel(const float* __restrict__ W3,
                                                  unsigned short* __restrict__ W3T) {
  const int k = blockIdx.x;           // 0..127
  for (int n = threadIdx.x; n < 1024; n += 256)
    W3T[n*128 + k] = f2h(W3[(size_t)k*1024 + n]);
}

// ---------------- W2 -> fp16 transposed [128][64] ----------------
__global__ __launch_bounds__(256) void w2t_kernel(const float* __restrict__ W2,
                                                  unsigned short* __restrict__ W2T) {
  const int id0 = blockIdx.x*256 + threadIdx.x;
  const int stride = gridDim.x * 256;
  for (int id = id0; id < 128*64; id += stride) {
    const int n = id >> 6, k = id & 63;
    W2T[n*64 + k] = f2h(W2[k*128 + n]);
  }
}

// ---------------- conv2 layer2: fp16 MFMA, 128 rows x 128 cols per block, one shot ----------------
// A = relu(bn(za)) fp16 staged in LDS (swizzled); B = W2T (16KB, L2-hot) direct to regs.
__global__ __launch_bounds__(256) void conv2_l2_mfma(
    const float* __restrict__ za, const float* __restrict__ ss,
    const unsigned short* __restrict__ W2T, const float* __restrict__ b2,
    float* __restrict__ zb) {
  __shared__ unsigned short As[128*64];
  const int r0 = blockIdx.x * 128;
  const int t = threadIdx.x;
  const int lane = t & 63, w = t >> 6;
  const int quad = lane >> 4, mcol = lane & 15;

  // stage A: 128 rows x 64 ch, relu(bn) -> fp16, swizzled
  {
    const int kb = t & 7;           // 16B block along K (8 halves), 8 blocks cover 64 ch
    const int rr = t >> 3;          // 32 rows per pass
    float sc[8], sh[8];
    #pragma unroll
    for (int q = 0; q < 8; ++q) { sc[q] = ss[kb*8 + q]; sh[q] = ss[64 + kb*8 + q]; }
    #pragma unroll
    for (int it = 0; it < 4; ++it) {
      const int r = rr + it*32;
      const float* src = za + (size_t)(r0 + r)*64 + kb*8;
      const float4 v0 = *(const float4*)(src);
      const float4 v1 = *(const float4*)(src + 4);
      union { unsigned short s[8]; uint4 v; } o;
      o.s[0] = f2h(fmaxf(v0.x*sc[0] + sh[0], 0.0f));
      o.s[1] = f2h(fmaxf(v0.y*sc[1] + sh[1], 0.0f));
      o.s[2] = f2h(fmaxf(v0.z*sc[2] + sh[2], 0.0f));
      o.s[3] = f2h(fmaxf(v0.w*sc[3] + sh[3], 0.0f));
      o.s[4] = f2h(fmaxf(v1.x*sc[4] + sh[4], 0.0f));
      o.s[5] = f2h(fmaxf(v1.y*sc[5] + sh[5], 0.0f));
      o.s[6] = f2h(fmaxf(v1.z*sc[6] + sh[6], 0.0f));
      o.s[7] = f2h(fmaxf(v1.w*sc[7] + sh[7], 0.0f));
      *(uint4*)(As + r*64 + ((kb ^ (r & 7)) * 8)) = o.v;
    }
  }
  __syncthreads();

  const int wrow = (w >> 1) * 64;
  const int wcol = (w & 1) * 64;

  f16x8 af[2][4], bfr[2][4];
  #pragma unroll
  for (int ks = 0; ks < 2; ++ks)
    #pragma unroll
    for (int mi = 0; mi < 4; ++mi) {
      const int row = wrow + mi*16 + mcol;
      af[ks][mi] = *(const f16x8*)(As + row*64 + (((ks*4 + quad) ^ (row & 7)) * 8));
    }
  #pragma unroll
  for (int ks = 0; ks < 2; ++ks)
    #pragma unroll
    for (int ni = 0; ni < 4; ++ni) {
      const int nr = wcol + ni*16 + mcol;
      bfr[ks][ni] = *(const f16x8*)(W2T + nr*64 + ks*32 + quad*8);
    }

  f32x4 acc[4][4];
  #pragma unroll
  for (int mi = 0; mi < 4; ++mi)
    #pragma unroll
    for (int ni = 0; ni < 4; ++ni)
      acc[mi][ni] = (f32x4){0.f, 0.f, 0.f, 0.f};

  #pragma unroll
  for (int ks = 0; ks < 2; ++ks)
    #pragma unroll
    for (int mi = 0; mi < 4; ++mi)
      #pragma unroll
      for (int ni = 0; ni < 4; ++ni)
        acc[mi][ni] = __builtin_amdgcn_mfma_f32_16x16x32_f16(af[ks][mi], bfr[ks][ni], acc[mi][ni], 0, 0, 0);

  // store: C/D layout col=lane&15, row=quad*4+j
  float bb[4];
  #pragma unroll
  for (int ni = 0; ni < 4; ++ni) bb[ni] = b2[wcol + ni*16 + mcol];
  #pragma unroll
  for (int mi = 0; mi < 4; ++mi) {
    const int rbase = r0 + wrow + mi*16 + quad*4;
    #pragma unroll
    for (int ni = 0; ni < 4; ++ni) {
      const int col = wcol + ni*16 + mcol;
      #pragma unroll
      for (int j = 0; j < 4; ++j)
        zb[(size_t)(rbase + j)*128 + col] = acc[mi][ni][j] + bb[ni];
    }
  }
}

// ---------------- conv2 layer3 + max: fp16 MFMA; A-frags in regs, B from L2,
// epilogue to LDS out-buffer (keeps vmcnt clean), single coalesced flush ----------------
__global__ __launch_bounds__(256, 2) void conv2_l3max_mfma(
    const float* __restrict__ zb, const float* __restrict__ ss,
    const unsigned short* __restrict__ W3T, const float* __restrict__ b3,
    float* __restrict__ x2) {
  __shared__ unsigned short As[128*128];
  __shared__ float Obuf[8*1024];
  const int r0 = blockIdx.x * 128;
  const int t = threadIdx.x;
  const int lane = t & 63, w = t >> 6;
  const int quad = lane >> 4, mcol = lane & 15;

  // ---- stage A: relu(bn(zb)) -> fp16, swizzled ----
  {
    const int kb = t & 15;          // 16B block along K (8 halves)
    const int rr = t >> 4;          // 16 rows per pass
    float sc[8], sh[8];
    #pragma unroll
    for (int q = 0; q < 8; ++q) { sc[q] = ss[kb*8 + q]; sh[q] = ss[128 + kb*8 + q]; }
    #pragma unroll
    for (int it = 0; it < 8; ++it) {
      const int r = rr + it*16;
      const float* src = zb + (size_t)(r0 + r)*128 + kb*8;
      const float4 v0 = *(const float4*)(src);
      const float4 v1 = *(const float4*)(src + 4);
      union { unsigned short s[8]; uint4 v; } o;
      o.s[0] = f2h(fmaxf(v0.x*sc[0] + sh[0], 0.0f));
      o.s[1] = f2h(fmaxf(v0.y*sc[1] + sh[1], 0.0f));
      o.s[2] = f2h(fmaxf(v0.z*sc[2] + sh[2], 0.0f));
      o.s[3] = f2h(fmaxf(v0.w*sc[3] + sh[3], 0.0f));
      o.s[4] = f2h(fmaxf(v1.x*sc[4] + sh[4], 0.0f));
      o.s[5] = f2h(fmaxf(v1.y*sc[5] + sh[5], 0.0f));
      o.s[6] = f2h(fmaxf(v1.z*sc[6] + sh[6], 0.0f));
      o.s[7] = f2h(fmaxf(v1.w*sc[7] + sh[7], 0.0f));
      *(uint4*)(As + r*128 + ((kb ^ (r & 7)) * 8)) = o.v;
    }
  }
  __syncthreads();

  const int wrow = (w >> 1) * 64;
  const int wcol = (w & 1) * 64;

  // A-fragments to registers once; reused across all 8 column chunks
  f16x8 af[4][4];   // [ks][mi]
  #pragma unroll
  for (int ks = 0; ks < 4; ++ks)
    #pragma unroll
    for (int mi = 0; mi < 4; ++mi) {
      const int row = wrow + mi*16 + mcol;
      af[ks][mi] = *(const f16x8*)(As + row*128 + (((ks*4 + quad) ^ (row & 7)) * 8));
    }

  #pragma unroll 1
  for (int chunk = 0; chunk < 8; ++chunk) {
    const int n0 = chunk * 128;

    f16x8 bfr[4][4];   // [ks][ni] — 16 coalesced 16B loads, L2-hot
    #pragma unroll
    for (int ks = 0; ks < 4; ++ks)
      #pragma unroll
      for (int ni = 0; ni < 4; ++ni) {
        const int nr = n0 + wcol + ni*16 + mcol;
        bfr[ks][ni] = *(const f16x8*)(W3T + (size_t)nr*128 + ks*32 + quad*8);
      }

    f32x4 acc[4][4];
    #pragma unroll
    for (int mi = 0; mi < 4; ++mi)
      #pragma unroll
      for (int ni = 0; ni < 4; ++ni)
        acc[mi][ni] = (f32x4){0.f, 0.f, 0.f, 0.f};

    #pragma unroll
    for (int ks = 0; ks < 4; ++ks)
      #pragma unroll
      for (int mi = 0; mi < 4; ++mi)
        #pragma unroll
        for (int ni = 0; ni < 4; ++ni)
          acc[mi][ni] = __builtin_amdgcn_mfma_f32_16x16x32_f16(af[ks][mi], bfr[ks][ni], acc[mi][ni], 0, 0, 0);

    // fused max over 16 rows of each tile (= one point) -> LDS out-buffer (no global stores here)
    #pragma unroll
    for (int mi = 0; mi < 4; ++mi) {
      const int pl = (w >> 1)*4 + mi;          // local point 0..7
      #pragma unroll
      for (int ni = 0; ni < 4; ++ni) {
        f32x4 a = acc[mi][ni];
        float m = fmaxf(fmaxf(a[0], a[1]), fmaxf(a[2], a[3]));
        m = fmaxf(m, __shfl_xor(m, 16));
        m = fmaxf(m, __shfl_xor(m, 32));
        if (quad == 0) Obuf[pl*1024 + n0 + wcol + ni*16 + mcol] = m;
      }
    }
  }
  __syncthreads();

  // flush: 8 points x 1024 cols, coalesced float4 + b3
  #pragma unroll
  for (int i = 0; i < 8; ++i) {
    const int idx4 = i*256 + t;          // float4 index in [0, 2048)
    const int p = idx4 >> 8, c4 = idx4 & 255;
    float4 v = *(float4*)(Obuf + idx4*4);
    const float4 bbv = *(const float4*)(b3 + c4*4);
    v.x += bbv.x; v.y += bbv.y; v.z += bbv.z; v.w += bbv.w;
    *(float4*)(x2 + (size_t)(blockIdx.x*8 + p)*1024 + c4*4) = v;
  }
}

// ---------------- global max pool, two coalesced stages ----------------
__global__ __launch_bounds__(256) void pool1_kernel(const float* __restrict__ x2,
                                                    float* __restrict__ pmax) {
  const int b = blockIdx.x >> 4, g = blockIdx.x & 15;
  const int t = threadIdx.x;
  const float* base = x2 + (size_t)(b*1024 + g*64)*1024;
  float m0 = -INFINITY, m1 = -INFINITY, m2 = -INFINITY, m3 = -INFINITY;
  for (int n = 0; n < 64; ++n) {
    const float* row = base + (size_t)n*1024;
    m0 = fmaxf(m0, row[t]);
    m1 = fmaxf(m1, row[t + 256]);
    m2 = fmaxf(m2, row[t + 512]);
    m3 = fmaxf(m3, row[t + 768]);
  }
  float* o = pmax + (size_t)blockIdx.x*1024;
  o[t] = m0; o[t+256] = m1; o[t+512] = m2; o[t+768] = m3;
}

__global__ __launch_bounds__(256) void pool2_kernel(const float* __restrict__ pmax,
                                                    float* __restrict__ g) {
  const int id = blockIdx.x*256 + threadIdx.x; // b*1024 + c
  const int b = id >> 10, c = id & 1023;
  float m = -INFINITY;
  for (int q = 0; q < 16; ++q) m = fmaxf(m, pmax[(size_t)(b*16 + q)*1024 + c]);
  g[id] = m;
}

// ---------------- final linear (partials over c-quarters) ----------------
__global__ __launch_bounds__(256) void lin_kernel(const float* __restrict__ g,
    const float* __restrict__ W, float* __restrict__ zpart) {
  const int b = blockIdx.x >> 2, q = blockIdx.x & 3;
  const int o = threadIdx.x;
  const float* gb = g + b*1024 + q*256;
  const float* Wq = W + q*256*256;
  float acc = 0.0f;
  for (int c = 0; c < 256; ++c) acc += gb[c] * Wq[c*256 + o];
  zpart[blockIdx.x*256 + o] = acc;
}

// ---------------- final BN(8 rows) + relu ----------------
__global__ __launch_bounds__(256) void final_kernel(const float* __restrict__ zpart,
    const float* __restrict__ lb, const float* __restrict__ lg,
    const float* __restrict__ lbe, float* __restrict__ out) {
  const int o = threadIdx.x;
  float z[NB]; float s = 0.0f, s2 = 0.0f;
  #pragma unroll
  for (int b = 0; b < NB; ++b) {
    float v = lb[o];
    #pragma unroll
    for (int q = 0; q < 4; ++q) v += zpart[(b*4+q)*256 + o];
    z[b] = v; s += v; s2 += v*v;
  }
  const float mu  = s * 0.125f;
  const float var = s2 * 0.125f - mu*mu;
  const float inv = rsqrtf(var + 1e-5f);
  const float sc = lg[o]*inv, sh = lbe[o] - mu*sc;
  #pragma unroll
  for (int b = 0; b < NB; ++b) out[b*256 + o] = fmaxf(z[b]*sc + sh, 0.0f);
}

extern "C" void kernel_launch(void* const* d_in, const int* in_sizes, int n_in,
                              void* d_out, int out_size, void* d_ws, size_t ws_size,
                              hipStream_t stream) {
  const float* pos    = (const float*)d_in[0];
  const float* c1_W1  = (const float*)d_in[2];
  const float* c1_b1  = (const float*)d_in[3];
  const float* c1_g1  = (const float*)d_in[4];
  const float* c1_be1 = (const float*)d_in[5];
  const float* c1_W2  = (const float*)d_in[6];
  const float* c1_b2  = (const float*)d_in[7];
  const float* c2_W1  = (const float*)d_in[8];
  const float* c2_b1  = (const float*)d_in[9];
  const float* c2_g1  = (const float*)d_in[10];
  const float* c2_be1 = (const float*)d_in[11];
  const float* c2_W2  = (const float*)d_in[12];
  const float* c2_b2  = (const float*)d_in[13];
  const float* c2_g2  = (const float*)d_in[14];
  const float* c2_be2 = (const float*)d_in[15];
  const float* c2_W3  = (const float*)d_in[16];
  const float* c2_b3  = (const float*)d_in[17];
  const float* lin_W  = (const float*)d_in[18];
  const float* lin_b  = (const float*)d_in[19];
  const float* lin_g  = (const float*)d_in[20];
  const float* lin_be = (const float*)d_in[21];
  float* out = (float*)d_out;

  char* ws = (char*)d_ws;
  int*   idx     = (int*)  (ws + 0);                 // 512 KB
  float* rel     = (float*)(ws + 524288);            // 1.5 MB
  float* ss1     = (float*)(ws + 2097152);           // 128
  float* ssA     = (float*)(ws + 2097152 + 512);     // 128
  float* ssB     = (float*)(ws + 2097152 + 1024);    // 256
  float* zpart   = (float*)(ws + 2097152 + 2048);    // 8192
  float* gpool   = (float*)(ws + 2097152 + 2048 + 32768);          // 8192
  float* partial = (float*)(ws + 2097152 + 2048 + 65536);          // up to 65536 floats
  unsigned short* W2T = (unsigned short*)(ws + 2164736 + 131072);  // 16 KB, after the C=64 partial region; C=128 stats pass (which would overlap) runs only after conv2_l2 consumed W2T
  float* bufA    = (float*)(ws + 2426880);           // 33.5 MB (z1 / za / x2)
  float* x1      = (float*)(ws + 35981312);          // 2 MB (x1, then W3T)
  unsigned short* W3T = (unsigned short*)(ws + 35981312);
  float* zb      = (float*)(ws + 38078464);          // 64 MB (zb, then pmax)
  float* pmax    = (float*)(ws + 38078464);

  const float invPK = 1.0f / (float)PK;

  knn_kernel<<<PTS/4, 256, 0, stream>>>(pos, idx, rel);
  conv1_l1_kernel<<<PK/64, 256, 0, stream>>>(pos, idx, rel, c1_W1, c1_b1, bufA);
  stats_partial_kernel<<<256, 256, 0, stream>>>(bufA, PK/256, 64, partial);
  stats_final_kernel<<<1, 256, 0, stream>>>(partial, 256, 64, invPK, c1_g1, c1_be1, ss1);
  conv1_l2max_kernel<<<PTS, 64, 0, stream>>>(bufA, ss1, c1_W2, c1_b2, x1);
  conv2_l1_kernel<<<PTS, 256, 0, stream>>>(x1, idx, rel, c2_W1, c2_b1, bufA);
  w3t_kernel<<<128, 256, 0, stream>>>(c2_W3, W3T);
  w2t_kernel<<<8, 256, 0, stream>>>(c2_W2, W2T);
  stats_partial_kernel<<<256, 256, 0, stream>>>(bufA, PK/256, 64, partial);
  stats_final_kernel<<<1, 256, 0, stream>>>(partial, 256, 64, invPK, c2_g1, c2_be1, ssA);
  conv2_l2_mfma<<<PK/128, 256, 0, stream>>>(bufA, ssA, W2T, c2_b2, zb);
  stats_partial_kernel<<<256, 256, 0, stream>>>(zb, PK/256, 128, partial);
  stats_final_kernel<<<1, 256, 0, stream>>>(partial, 256, 128, invPK, c2_g2, c2_be2, ssB);
  conv2_l3max_mfma<<<PK/128, 256, 0, stream>>>(zb, ssB, W3T, c2_b3, bufA);
  pool1_kernel<<<NB*16, 256, 0, stream>>>(bufA, pmax);
  pool2_kernel<<<PTS/256, 256, 0, stream>>>(pmax, gpool);
  lin_kernel<<<32, 256, 0, stream>>>(gpool, lin_W, zpart);
  final_kernel<<<1, 256, 0, stream>>>(zpart, lin_b, lin_g, lin_be, out);
}

// Round 8
// 558.266 us; speedup vs baseline: 1.2629x; 1.1565x over previous
//
#include <hip/hip_runtime.h>
#include <math.h>

#define NB   8
#define NPTS 1024
#define PTS  8192      // NB*NPTS
#define KNN  16
#define PK   (PTS*KNN) // 131072

typedef __attribute__((ext_vector_type(8))) _Float16 f16x8;
typedef __attribute__((ext_vector_type(4))) float f32x4;

__device__ __forceinline__ unsigned short f2h(float f) {
  _Float16 h = (_Float16)f;
  union { _Float16 h; unsigned short u; } c; c.h = h;
  return c.u;
}
__device__ __forceinline__ float h2f(unsigned short u) {
  union { unsigned short u; _Float16 h; } c; c.u = u;
  return (float)c.h;
}

// ---------------- kNN: one WAVE per point; register-resident top-16, barrier-free ----------------
__global__ __launch_bounds__(256) void knn_kernel(const float* __restrict__ pos,
                                                  int* __restrict__ idx,
                                                  float* __restrict__ rel) {
  __shared__ float px[NPTS], py[NPTS], pz[NPTS];
  const int t = threadIdx.x;
  const int wv = t >> 6, lane = t & 63;
  const int b = blockIdx.x;
  const int graph = b >> 8;             // 256 blocks per graph
  const int base = graph << 10;
  for (int j = t; j < NPTS; j += 256) {
    px[j] = pos[3*(base+j)];
    py[j] = pos[3*(base+j)+1];
    pz[j] = pos[3*(base+j)+2];
  }
  __syncthreads();

  const int il = ((b & 255) << 2) + wv; // point index within graph
  const float pix = px[il], piy = py[il], piz = pz[il];
  const float sqi = pix*pix + piy*piy + piz*piz;

  float d[16];
  #pragma unroll
  for (int q = 0; q < 16; ++q) {
    const int j = (q << 6) + lane;
    const float x = px[j], y = py[j], z = pz[j];
    const float sqj = x*x + y*y + z*z;
    const float dt  = pix*x + piy*y + piz*z;
    d[q] = sqi + sqj - 2.0f*dt;
  }
  float mv = d[0]; int mq = 0;
  #pragma unroll
  for (int q = 1; q < 16; ++q) { if (d[q] < mv) { mv = d[q]; mq = q; } }

  int sel = 0;
  for (int s = 0; s < KNN; ++s) {
    float v = mv; int j = (mq << 6) + lane;
    #pragma unroll
    for (int m = 1; m <= 32; m <<= 1) {
      const float v2 = __shfl_xor(v, m);
      const int   j2 = __shfl_xor(j, m);
      if (v2 < v || (v2 == v && j2 < j)) { v = v2; j = j2; }
    }
    if (lane == s) sel = j;
    if (lane == (j & 63)) {
      const int wq = j >> 6;
      #pragma unroll
      for (int q = 0; q < 16; ++q) if (q == wq) d[q] = INFINITY;
      mv = d[0]; mq = 0;
      #pragma unroll
      for (int q = 1; q < 16; ++q) { if (d[q] < mv) { mv = d[q]; mq = q; } }
    }
  }

  if (lane < KNN) {
    const int i = base + il;
    const int r = i*KNN + lane;
    idx[r] = base + sel;
    rel[3*r]   = px[sel] - pix;
    rel[3*r+1] = py[sel] - piy;
    rel[3*r+2] = pz[sel] - piz;
  }
}

// ---------------- conv1 layer1 ----------------
__global__ __launch_bounds__(256) void conv1_l1_kernel(const float* __restrict__ pos,
    const int* __restrict__ idx, const float* __restrict__ rel,
    const float* __restrict__ W1, const float* __restrict__ b1,
    float* __restrict__ z1) {
  const int r0 = blockIdx.x * 64;
  const int t = threadIdx.x;
  __shared__ float f[64][6];
  if (t < 64) {
    const int r = r0 + t;
    const int j = idx[r];
    f[t][0] = pos[3*j]; f[t][1] = pos[3*j+1]; f[t][2] = pos[3*j+2];
    f[t][3] = rel[3*r]; f[t][4] = rel[3*r+1]; f[t][5] = rel[3*r+2];
  }
  __syncthreads();
  const int c = t & 63, rg = t >> 6;
  float w[6];
  #pragma unroll
  for (int q = 0; q < 6; ++q) w[q] = W1[q*64 + c];
  const float bb = b1[c];
  for (int j = 0; j < 16; ++j) {
    const int lr = rg + 4*j;
    float z = bb;
    #pragma unroll
    for (int q = 0; q < 6; ++q) z += f[lr][q]*w[q];
    z1[(size_t)(r0+lr)*64 + c] = z;
  }
}

// ---------------- BN stats (generic two-stage, used for C=64 passes) ----------------
__global__ __launch_bounds__(256) void stats_partial_kernel(const float* __restrict__ z,
    int rowsPerBlock, int C, float* __restrict__ partial) {
  const int t = threadIdx.x;
  const int c = t & (C-1);
  const int rl = t / C;
  const int RL = 256 / C;
  const int r0 = blockIdx.x * rowsPerBlock;
  float s = 0.0f, s2 = 0.0f;
  for (int r = rl; r < rowsPerBlock; r += RL) {
    const float v = z[(size_t)(r0 + r)*C + c];
    s += v; s2 += v*v;
  }
  __shared__ float ls[256], ls2[256];
  ls[t] = s; ls2[t] = s2;
  __syncthreads();
  if (t < C) {
    float a = ls[t], a2 = ls2[t];
    for (int q = 1; q < RL; ++q) { a += ls[t + q*C]; a2 += ls2[t + q*C]; }
    partial[blockIdx.x*2*C + t]     = a;
    partial[blockIdx.x*2*C + C + t] = a2;
  }
}

__global__ __launch_bounds__(256) void stats_final_kernel(const float* __restrict__ partial,
    int G, int C, float invRows,
    const float* __restrict__ gamma, const float* __restrict__ beta,
    float* __restrict__ ss) {
  const int t = threadIdx.x;
  if (t >= C) return;
  float s = 0.0f, s2 = 0.0f;
  for (int g = 0; g < G; ++g) { s += partial[g*2*C + t]; s2 += partial[g*2*C + C + t]; }
  const float mu  = s * invRows;
  const float var = s2 * invRows - mu*mu;
  const float sc  = gamma[t] * rsqrtf(var + 1e-5f);
  ss[t] = sc; ss[C + t] = beta[t] - mu*sc;
}

// ---------------- sum columns of [G][256] partial blocks: 64 blocks x 16 groups ----------------
__global__ __launch_bounds__(256) void sumcols_kernel(const float* __restrict__ partial,
                                                      float* __restrict__ mid) {
  const int b = blockIdx.x, t = threadIdx.x;
  float a = 0.0f;
  #pragma unroll
  for (int i = 0; i < 16; ++i) a += partial[(size_t)(b*16 + i)*256 + t];
  mid[b*256 + t] = a;
}

// ---------------- conv1 layer2 + max: 4 points per block (one wave each) ----------------
__global__ __launch_bounds__(256) void conv1_l2max_kernel(const float* __restrict__ z1,
    const float* __restrict__ ss, const float* __restrict__ W2,
    const float* __restrict__ b2, float* __restrict__ x1) {
  __shared__ float h[4][KNN][64];
  const int wv = threadIdx.x >> 6, t = threadIdx.x & 63;
  const int i = blockIdx.x*4 + wv;
  const float sc = ss[t], sh = ss[64+t];
  #pragma unroll
  for (int k = 0; k < KNN; ++k) {
    const float z = z1[(size_t)(i*KNN+k)*64 + t];
    h[wv][k][t] = fmaxf(z*sc + sh, 0.0f);
  }
  __syncthreads();
  float w[64];
  #pragma unroll
  for (int d = 0; d < 64; ++d) w[d] = W2[d*64 + t];
  const float bb = b2[t];
  float acc = -INFINITY;
  for (int k = 0; k < KNN; ++k) {
    float y = bb;
    #pragma unroll
    for (int d = 0; d < 64; ++d) y += h[wv][k][d]*w[d];
    acc = fmaxf(acc, y);
  }
  x1[(size_t)i*64 + t] = acc;
}

// ---------------- conv2 layer1 ----------------
__global__ __launch_bounds__(256) void conv2_l1_kernel(const float* __restrict__ x1,
    const int* __restrict__ idx, const float* __restrict__ rel,
    const float* __restrict__ W, const float* __restrict__ bias,
    float* __restrict__ za) {
  const int i = blockIdx.x;
  const int t = threadIdx.x;
  const int c = t & 63, kg = t >> 6;
  __shared__ float xg[KNN][64];
  __shared__ float rl[KNN][3];
  #pragma unroll
  for (int j = 0; j < 4; ++j) {
    const int k = kg + 4*j;
    const int gj = idx[i*KNN + k];
    xg[k][c] = x1[(size_t)gj*64 + c];
  }
  if (t < KNN*3) rl[t/3][t%3] = rel[i*KNN*3 + t];
  __syncthreads();
  float w[67];
  #pragma unroll
  for (int q = 0; q < 67; ++q) w[q] = W[q*64 + c];
  const float bb = bias[c];
  #pragma unroll
  for (int j = 0; j < 4; ++j) {
    const int k = kg + 4*j;
    float y = bb + rl[k][0]*w[64] + rl[k][1]*w[65] + rl[k][2]*w[66];
    #pragma unroll
    for (int q = 0; q < 64; ++q) y += xg[k][q]*w[q];
    za[(size_t)(i*KNN+k)*64 + c] = y;
  }
}

// ---------------- W3 -> fp16 transposed [1024][128] ----------------
__global__ __launch_bounds__(256) void w3t_kernel(const float* __restrict__ W3,
                                                  unsigned short* __restrict__ W3T) {
  const int k = blockIdx.x;           // 0..127
  for (int n = threadIdx.x; n < 1024; n += 256)
    W3T[n*128 + k] = f2h(W3[(size_t)k*1024 + n]);
}

// ---------------- W2 -> fp16 transposed [128][64] ----------------
__global__ __launch_bounds__(256) void w2t_kernel(const float* __restrict__ W2,
                                                  unsigned short* __restrict__ W2T) {
  const int id0 = blockIdx.x*256 + threadIdx.x;
  const int stride = gridDim.x * 256;
  for (int id = id0; id < 128*64; id += stride) {
    const int n = id >> 6, k = id & 63;
    W2T[n*64 + k] = f2h(W2[k*128 + n]);
  }
}

// ---------------- conv2 layer2: fp16 MFMA + fused BN-stats; writes zb as fp16 ----------------
// A = relu(bn(za)) fp16 in LDS; B = W2T (16KB, L2-hot) to regs. Output tile repacked
// to fp16 through LDS for coalesced stores; per-block sum/sumsq partials emitted.
__global__ __launch_bounds__(256) void conv2_l2_mfma(
    const float* __restrict__ za, const float* __restrict__ ss,
    const unsigned short* __restrict__ W2T, const float* __restrict__ b2,
    unsigned short* __restrict__ zhb, float* __restrict__ partialB) {
  __shared__ unsigned short S[128*128];   // first 16KB: As; later: fp16 out tile
  __shared__ float ps[512];               // [rowhalf][{sum128,sumsq128}]
  const int r0 = blockIdx.x * 128;
  const int t = threadIdx.x;
  const int lane = t & 63, w = t >> 6;
  const int quad = lane >> 4, mcol = lane & 15;

  // stage A: 128 rows x 64 ch, relu(bn) -> fp16, swizzled
  {
    const int kb = t & 7;           // 16B block along K
    const int rr = t >> 3;          // 32 rows per pass
    float sc[8], sh[8];
    #pragma unroll
    for (int q = 0; q < 8; ++q) { sc[q] = ss[kb*8 + q]; sh[q] = ss[64 + kb*8 + q]; }
    #pragma unroll
    for (int it = 0; it < 4; ++it) {
      const int r = rr + it*32;
      const float* src = za + (size_t)(r0 + r)*64 + kb*8;
      const float4 v0 = *(const float4*)(src);
      const float4 v1 = *(const float4*)(src + 4);
      union { unsigned short s[8]; uint4 v; } o;
      o.s[0] = f2h(fmaxf(v0.x*sc[0] + sh[0], 0.0f));
      o.s[1] = f2h(fmaxf(v0.y*sc[1] + sh[1], 0.0f));
      o.s[2] = f2h(fmaxf(v0.z*sc[2] + sh[2], 0.0f));
      o.s[3] = f2h(fmaxf(v0.w*sc[3] + sh[3], 0.0f));
      o.s[4] = f2h(fmaxf(v1.x*sc[4] + sh[4], 0.0f));
      o.s[5] = f2h(fmaxf(v1.y*sc[5] + sh[5], 0.0f));
      o.s[6] = f2h(fmaxf(v1.z*sc[6] + sh[6], 0.0f));
      o.s[7] = f2h(fmaxf(v1.w*sc[7] + sh[7], 0.0f));
      *(uint4*)(S + r*64 + ((kb ^ (r & 7)) * 8)) = o.v;
    }
  }
  __syncthreads();

  const int wrow = (w >> 1) * 64;
  const int wcol = (w & 1) * 64;

  f16x8 af[2][4], bfr[2][4];
  #pragma unroll
  for (int ks = 0; ks < 2; ++ks)
    #pragma unroll
    for (int mi = 0; mi < 4; ++mi) {
      const int row = wrow + mi*16 + mcol;
      af[ks][mi] = *(const f16x8*)(S + row*64 + (((ks*4 + quad) ^ (row & 7)) * 8));
    }
  #pragma unroll
  for (int ks = 0; ks < 2; ++ks)
    #pragma unroll
    for (int ni = 0; ni < 4; ++ni) {
      const int nr = wcol + ni*16 + mcol;
      bfr[ks][ni] = *(const f16x8*)(W2T + nr*64 + ks*32 + quad*8);
    }

  f32x4 acc[4][4];
  #pragma unroll
  for (int mi = 0; mi < 4; ++mi)
    #pragma unroll
    for (int ni = 0; ni < 4; ++ni)
      acc[mi][ni] = (f32x4){0.f, 0.f, 0.f, 0.f};

  #pragma unroll
  for (int ks = 0; ks < 2; ++ks)
    #pragma unroll
    for (int mi = 0; mi < 4; ++mi)
      #pragma unroll
      for (int ni = 0; ni < 4; ++ni)
        acc[mi][ni] = __builtin_amdgcn_mfma_f32_16x16x32_f16(af[ks][mi], bfr[ks][ni], acc[mi][ni], 0, 0, 0);

  __syncthreads();   // all waves done reading As; S reusable as out tile

  // z = acc + bias: fp16 into S (swizzled 8-elem groups), sums into registers
  float bb[4];
  #pragma unroll
  for (int ni = 0; ni < 4; ++ni) bb[ni] = b2[wcol + ni*16 + mcol];
  float s[4] = {0,0,0,0}, s2[4] = {0,0,0,0};
  #pragma unroll
  for (int mi = 0; mi < 4; ++mi) {
    #pragma unroll
    for (int ni = 0; ni < 4; ++ni) {
      const int col = wcol + ni*16 + mcol;
      const int g = col >> 3, o = col & 7;
      #pragma unroll
      for (int j = 0; j < 4; ++j) {
        const int row = wrow + mi*16 + quad*4 + j;
        const float v = acc[mi][ni][j] + bb[ni];
        S[row*128 + ((g ^ (row & 15)) << 3) + o] = f2h(v);
        s[ni] += v; s2[ni] += v*v;
      }
    }
  }
  // reduce over this wave's 64 rows (quad groups)
  #pragma unroll
  for (int ni = 0; ni < 4; ++ni) {
    s[ni]  += __shfl_xor(s[ni], 16);  s[ni]  += __shfl_xor(s[ni], 32);
    s2[ni] += __shfl_xor(s2[ni], 16); s2[ni] += __shfl_xor(s2[ni], 32);
  }
  if (quad == 0) {
    const int rh = w >> 1;
    #pragma unroll
    for (int ni = 0; ni < 4; ++ni) {
      const int col = wcol + ni*16 + mcol;
      ps[rh*256 + col]       = s[ni];
      ps[rh*256 + 128 + col] = s2[ni];
    }
  }
  __syncthreads();

  // coalesced fp16 tile flush: 2048 uint4
  #pragma unroll
  for (int i = 0; i < 8; ++i) {
    const int u = i*256 + t;
    const int row = u >> 4, gg = u & 15;
    *(uint4*)(zhb + (size_t)(r0 + row)*128 + gg*8) =
        *(const uint4*)(S + row*128 + ((gg ^ (row & 15)) << 3));
  }
  // combined block partials: [block][sum128 | sumsq128]
  partialB[(size_t)blockIdx.x*256 + t] = ps[t] + ps[256 + t];
}

// ---------------- conv2 layer3 + max: fp16 MFMA, col-split grid (2048 blocks) ----------------
// Each block: 128 rows x 512 cols (4 chunks). A from fp16 zhb; B from L2; results via LDS Obuf.
__global__ __launch_bounds__(256, 3) void conv2_l3max_mfma(
    const unsigned short* __restrict__ zhb, const float* __restrict__ ss,
    const unsigned short* __restrict__ W3T, const float* __restrict__ b3,
    float* __restrict__ x2) {
  __shared__ unsigned short As[128*128];
  __shared__ float Obuf[8*512];
  const int rb = blockIdx.x >> 1, ch = blockIdx.x & 1;
  const int r0 = rb * 128;
  const int t = threadIdx.x;
  const int lane = t & 63, w = t >> 6;
  const int quad = lane >> 4, mcol = lane & 15;

  // ---- stage A: relu(bn(zhb)) fp16 -> fp16, swizzled ----
  {
    const int kb = t & 15;          // 16B block along K (8 halves)
    const int rr = t >> 4;          // 16 rows per pass
    float sc[8], sh[8];
    #pragma unroll
    for (int q = 0; q < 8; ++q) { sc[q] = ss[kb*8 + q]; sh[q] = ss[128 + kb*8 + q]; }
    #pragma unroll
    for (int it = 0; it < 8; ++it) {
      const int r = rr + it*16;
      union { uint4 v; unsigned short s[8]; } in;
      in.v = *(const uint4*)(zhb + (size_t)(r0 + r)*128 + kb*8);
      union { unsigned short s[8]; uint4 v; } o;
      #pragma unroll
      for (int q = 0; q < 8; ++q)
        o.s[q] = f2h(fmaxf(h2f(in.s[q])*sc[q] + sh[q], 0.0f));
      *(uint4*)(As + r*128 + ((kb ^ (r & 7)) * 8)) = o.v;
    }
  }
  __syncthreads();

  const int wrow = (w >> 1) * 64;
  const int wcol = (w & 1) * 64;

  #pragma unroll 1
  for (int chunk = 0; chunk < 4; ++chunk) {
    const int n0 = ch*512 + chunk*128;

    f16x8 bfr[4][4];   // 16 coalesced 16B loads, L2-hot
    #pragma unroll
    for (int ks = 0; ks < 4; ++ks)
      #pragma unroll
      for (int ni = 0; ni < 4; ++ni) {
        const int nr = n0 + wcol + ni*16 + mcol;
        bfr[ks][ni] = *(const f16x8*)(W3T + (size_t)nr*128 + ks*32 + quad*8);
      }

    f32x4 acc[4][4];
    #pragma unroll
    for (int mi = 0; mi < 4; ++mi)
      #pragma unroll
      for (int ni = 0; ni < 4; ++ni)
        acc[mi][ni] = (f32x4){0.f, 0.f, 0.f, 0.f};

    #pragma unroll
    for (int ks = 0; ks < 4; ++ks) {
      f16x8 af[4];
      #pragma unroll
      for (int mi = 0; mi < 4; ++mi) {
        const int row = wrow + mi*16 + mcol;
        af[mi] = *(const f16x8*)(As + row*128 + (((ks*4 + quad) ^ (row & 7)) * 8));
      }
      #pragma unroll
      for (int mi = 0; mi < 4; ++mi)
        #pragma unroll
        for (int ni = 0; ni < 4; ++ni)
          acc[mi][ni] = __builtin_amdgcn_mfma_f32_16x16x32_f16(af[mi], bfr[ks][ni], acc[mi][ni], 0, 0, 0);
    }

    // fused max over 16 rows of each tile -> LDS out-buffer
    #pragma unroll
    for (int mi = 0; mi < 4; ++mi) {
      const int pl = (w >> 1)*4 + mi;          // local point 0..7
      #pragma unroll
      for (int ni = 0; ni < 4; ++ni) {
        f32x4 a = acc[mi][ni];
        float m = fmaxf(fmaxf(a[0], a[1]), fmaxf(a[2], a[3]));
        m = fmaxf(m, __shfl_xor(m, 16));
        m = fmaxf(m, __shfl_xor(m, 32));
        if (quad == 0) Obuf[pl*512 + chunk*128 + wcol + ni*16 + mcol] = m;
      }
    }
  }
  __syncthreads();

  // flush: 8 points x 512 cols, coalesced float4 + b3
  #pragma unroll
  for (int i = 0; i < 4; ++i) {
    const int idx4 = i*256 + t;          // float4 index in [0, 1024)
    const int p = idx4 >> 7, c4 = idx4 & 127;
    const int col = ch*512 + c4*4;
    float4 v = *(float4*)(Obuf + p*512 + c4*4);
    const float4 bbv = *(const float4*)(b3 + col);
    v.x += bbv.x; v.y += bbv.y; v.z += bbv.z; v.w += bbv.w;
    *(float4*)(x2 + (size_t)(rb*8 + p)*1024 + col) = v;
  }
}

// ---------------- global max pool, two coalesced stages ----------------
__global__ __launch_bounds__(256) void pool1_kernel(const float* __restrict__ x2,
                                                    float* __restrict__ pmax) {
  const int b = blockIdx.x >> 6, g = blockIdx.x & 63;
  const int t = threadIdx.x;
  const float* base = x2 + (size_t)(b*1024 + g*16)*1024;
  float m0 = -INFINITY, m1 = -INFINITY, m2 = -INFINITY, m3 = -INFINITY;
  for (int n = 0; n < 16; ++n) {
    const float* row = base + (size_t)n*1024;
    m0 = fmaxf(m0, row[t]);
    m1 = fmaxf(m1, row[t + 256]);
    m2 = fmaxf(m2, row[t + 512]);
    m3 = fmaxf(m3, row[t + 768]);
  }
  float* o = pmax + (size_t)blockIdx.x*1024;
  o[t] = m0; o[t+256] = m1; o[t+512] = m2; o[t+768] = m3;
}

__global__ __launch_bounds__(256) void pool2_kernel(const float* __restrict__ pmax,
                                                    float* __restrict__ g) {
  const int id = blockIdx.x*256 + threadIdx.x; // b*1024 + c
  const int b = id >> 10, c = id & 1023;
  float m = -INFINITY;
  for (int q = 0; q < 64; ++q) m = fmaxf(m, pmax[(size_t)(b*64 + q)*1024 + c]);
  g[id] = m;
}

// ---------------- final linear (partials over c-quarters) ----------------
__global__ __launch_bounds__(256) void lin_kernel(const float* __restrict__ g,
    const float* __restrict__ W, float* __restrict__ zpart) {
  const int b = blockIdx.x >> 2, q = blockIdx.x & 3;
  const int o = threadIdx.x;
  const float* gb = g + b*1024 + q*256;
  const float* Wq = W + q*256*256;
  float acc = 0.0f;
  for (int c = 0; c < 256; ++c) acc += gb[c] * Wq[c*256 + o];
  zpart[blockIdx.x*256 + o] = acc;
}

// ---------------- final BN(8 rows) + relu ----------------
__global__ __launch_bounds__(256) void final_kernel(const float* __restrict__ zpart,
    const float* __restrict__ lb, const float* __restrict__ lg,
    const float* __restrict__ lbe, float* __restrict__ out) {
  const int o = threadIdx.x;
  float z[NB]; float s = 0.0f, s2 = 0.0f;
  #pragma unroll
  for (int b = 0; b < NB; ++b) {
    float v = lb[o];
    #pragma unroll
    for (int q = 0; q < 4; ++q) v += zpart[(b*4+q)*256 + o];
    z[b] = v; s += v; s2 += v*v;
  }
  const float mu  = s * 0.125f;
  const float var = s2 * 0.125f - mu*mu;
  const float inv = rsqrtf(var + 1e-5f);
  const float sc = lg[o]*inv, sh = lbe[o] - mu*sc;
  #pragma unroll
  for (int b = 0; b < NB; ++b) out[b*256 + o] = fmaxf(z[b]*sc + sh, 0.0f);
}

extern "C" void kernel_launch(void* const* d_in, const int* in_sizes, int n_in,
                              void* d_out, int out_size, void* d_ws, size_t ws_size,
                              hipStream_t stream) {
  const float* pos    = (const float*)d_in[0];
  const float* c1_W1  = (const float*)d_in[2];
  const float* c1_b1  = (const float*)d_in[3];
  const float* c1_g1  = (const float*)d_in[4];
  const float* c1_be1 = (const float*)d_in[5];
  const float* c1_W2  = (const float*)d_in[6];
  const float* c1_b2  = (const float*)d_in[7];
  const float* c2_W1  = (const float*)d_in[8];
  const float* c2_b1  = (const float*)d_in[9];
  const float* c2_g1  = (const float*)d_in[10];
  const float* c2_be1 = (const float*)d_in[11];
  const float* c2_W2  = (const float*)d_in[12];
  const float* c2_b2  = (const float*)d_in[13];
  const float* c2_g2  = (const float*)d_in[14];
  const float* c2_be2 = (const float*)d_in[15];
  const float* c2_W3  = (const float*)d_in[16];
  const float* c2_b3  = (const float*)d_in[17];
  const float* lin_W  = (const float*)d_in[18];
  const float* lin_b  = (const float*)d_in[19];
  const float* lin_g  = (const float*)d_in[20];
  const float* lin_be = (const float*)d_in[21];
  float* out = (float*)d_out;

  char* ws = (char*)d_ws;
  int*   idx     = (int*)  (ws + 0);                 // 512 KB
  float* rel     = (float*)(ws + 524288);            // 1.5 MB
  float* ss1     = (float*)(ws + 2097152);           // 128
  float* ssA     = (float*)(ws + 2097152 + 512);     // 128
  float* ssB     = (float*)(ws + 2097152 + 1024);    // 256
  float* zpart   = (float*)(ws + 2097152 + 2048);    // 8192
  float* gpool   = (float*)(ws + 2097152 + 2048 + 32768);          // 8192
  float* partial = (float*)(ws + 2097152 + 2048 + 65536);          // 128 KB (C=64 passes)
  unsigned short* W2T = (unsigned short*)(ws + 2164736 + 131072);  // 16 KB
  float* bufA    = (float*)(ws + 2426880);           // 33.5 MB (z1 / za / x2)
  float* x1      = (float*)(ws + 35981312);          // 2 MB (x1, then W3T)
  unsigned short* W3T = (unsigned short*)(ws + 35981312);
  unsigned short* zhb = (unsigned short*)(ws + 38078464);  // 33.5 MB fp16 zb; later pmax reuse
  float* pmax    = (float*)(ws + 38078464);                // 2 MB (after l3max consumed zhb)
  float* partialB= (float*)(ws + 71632896);          // 1 MB  (1024 x 256)
  float* midB    = (float*)(ws + 72681472);          // 64 KB (64 x 256)

  const float invPK = 1.0f / (float)PK;

  knn_kernel<<<PTS/4, 256, 0, stream>>>(pos, idx, rel);
  conv1_l1_kernel<<<PK/64, 256, 0, stream>>>(pos, idx, rel, c1_W1, c1_b1, bufA);
  stats_partial_kernel<<<256, 256, 0, stream>>>(bufA, PK/256, 64, partial);
  stats_final_kernel<<<1, 256, 0, stream>>>(partial, 256, 64, invPK, c1_g1, c1_be1, ss1);
  conv1_l2max_kernel<<<PTS/4, 256, 0, stream>>>(bufA, ss1, c1_W2, c1_b2, x1);
  conv2_l1_kernel<<<PTS, 256, 0, stream>>>(x1, idx, rel, c2_W1, c2_b1, bufA);
  w3t_kernel<<<128, 256, 0, stream>>>(c2_W3, W3T);
  w2t_kernel<<<8, 256, 0, stream>>>(c2_W2, W2T);
  stats_partial_kernel<<<256, 256, 0, stream>>>(bufA, PK/256, 64, partial);
  stats_final_kernel<<<1, 256, 0, stream>>>(partial, 256, 64, invPK, c2_g1, c2_be1, ssA);
  conv2_l2_mfma<<<PK/128, 256, 0, stream>>>(bufA, ssA, W2T, c2_b2, zhb, partialB);
  sumcols_kernel<<<64, 256, 0, stream>>>(partialB, midB);
  stats_final_kernel<<<1, 256, 0, stream>>>(midB, 64, 128, invPK, c2_g2, c2_be2, ssB);
  conv2_l3max_mfma<<<PK/64, 256, 0, stream>>>(zhb, ssB, W3T, c2_b3, bufA);
  pool1_kernel<<<NB*64, 256, 0, stream>>>(bufA, pmax);
  pool2_kernel<<<PTS/256, 256, 0, stream>>>(pmax, gpool);
  lin_kernel<<<32, 256, 0, stream>>>(gpool, lin_W, zpart);
  final_kernel<<<1, 256, 0, stream>>>(zpart, lin_b, lin_g, lin_be, out);
}

// Round 9
// 508.401 us; speedup vs baseline: 1.3868x; 1.0981x over previous
//
#include <hip/hip_runtime.h>
#include <math.h>

#define NB   8
#define NPTS 1024
#define PTS  8192      // NB*NPTS
#define KNN  16
#define PK   (PTS*KNN) // 131072

typedef __attribute__((ext_vector_type(8))) _Float16 f16x8;
typedef __attribute__((ext_vector_type(4))) float f32x4;

__device__ __forceinline__ unsigned short f2h(float f) {
  _Float16 h = (_Float16)f;
  union { _Float16 h; unsigned short u; } c; c.h = h;
  return c.u;
}
__device__ __forceinline__ float h2f(unsigned short u) {
  union { unsigned short u; _Float16 h; } c; c.u = u;
  return (float)c.h;
}

// ---------------- kNN: one WAVE per point; register-resident top-16, barrier-free ----------------
__global__ __launch_bounds__(256) void knn_kernel(const float* __restrict__ pos,
                                                  int* __restrict__ idx,
                                                  float* __restrict__ rel) {
  __shared__ float px[NPTS], py[NPTS], pz[NPTS];
  const int t = threadIdx.x;
  const int wv = t >> 6, lane = t & 63;
  const int b = blockIdx.x;
  const int graph = b >> 8;             // 256 blocks per graph
  const int base = graph << 10;
  for (int j = t; j < NPTS; j += 256) {
    px[j] = pos[3*(base+j)];
    py[j] = pos[3*(base+j)+1];
    pz[j] = pos[3*(base+j)+2];
  }
  __syncthreads();

  const int il = ((b & 255) << 2) + wv; // point index within graph
  const float pix = px[il], piy = py[il], piz = pz[il];
  const float sqi = pix*pix + piy*piy + piz*piz;

  float d[16];
  #pragma unroll
  for (int q = 0; q < 16; ++q) {
    const int j = (q << 6) + lane;
    const float x = px[j], y = py[j], z = pz[j];
    const float sqj = x*x + y*y + z*z;
    const float dt  = pix*x + piy*y + piz*z;
    d[q] = sqi + sqj - 2.0f*dt;
  }
  float mv = d[0]; int mq = 0;
  #pragma unroll
  for (int q = 1; q < 16; ++q) { if (d[q] < mv) { mv = d[q]; mq = q; } }

  int sel = 0;
  for (int s = 0; s < KNN; ++s) {
    float v = mv; int j = (mq << 6) + lane;
    #pragma unroll
    for (int m = 1; m <= 32; m <<= 1) {
      const float v2 = __shfl_xor(v, m);
      const int   j2 = __shfl_xor(j, m);
      if (v2 < v || (v2 == v && j2 < j)) { v = v2; j = j2; }
    }
    if (lane == s) sel = j;
    if (lane == (j & 63)) {
      const int wq = j >> 6;
      #pragma unroll
      for (int q = 0; q < 16; ++q) if (q == wq) d[q] = INFINITY;
      mv = d[0]; mq = 0;
      #pragma unroll
      for (int q = 1; q < 16; ++q) { if (d[q] < mv) { mv = d[q]; mq = q; } }
    }
  }

  if (lane < KNN) {
    const int i = base + il;
    const int r = i*KNN + lane;
    idx[r] = base + sel;
    rel[3*r]   = px[sel] - pix;
    rel[3*r+1] = py[sel] - piy;
    rel[3*r+2] = pz[sel] - piz;
  }
}

// ---------------- conv1 layer1 + fused BN partials ----------------
__global__ __launch_bounds__(256) void conv1_l1_kernel(const float* __restrict__ pos,
    const int* __restrict__ idx, const float* __restrict__ rel,
    const float* __restrict__ W1, const float* __restrict__ b1,
    float* __restrict__ z1, float* __restrict__ partial) {
  const int r0 = blockIdx.x * 64;
  const int t = threadIdx.x;
  __shared__ float f[64][6];
  __shared__ float ls[256], ls2[256];
  if (t < 64) {
    const int r = r0 + t;
    const int j = idx[r];
    f[t][0] = pos[3*j]; f[t][1] = pos[3*j+1]; f[t][2] = pos[3*j+2];
    f[t][3] = rel[3*r]; f[t][4] = rel[3*r+1]; f[t][5] = rel[3*r+2];
  }
  __syncthreads();
  const int c = t & 63, rg = t >> 6;
  float w[6];
  #pragma unroll
  for (int q = 0; q < 6; ++q) w[q] = W1[q*64 + c];
  const float bb = b1[c];
  float s = 0.0f, s2 = 0.0f;
  for (int j = 0; j < 16; ++j) {
    const int lr = rg + 4*j;
    float z = bb;
    #pragma unroll
    for (int q = 0; q < 6; ++q) z += f[lr][q]*w[q];
    z1[(size_t)(r0+lr)*64 + c] = z;
    s += z; s2 += z*z;
  }
  ls[t] = s; ls2[t] = s2;
  __syncthreads();
  if (t < 64) {
    float a = ls[t] + ls[t+64] + ls[t+128] + ls[t+192];
    float a2 = ls2[t] + ls2[t+64] + ls2[t+128] + ls2[t+192];
    partial[(size_t)blockIdx.x*128 + t]      = a;
    partial[(size_t)blockIdx.x*128 + 64 + t] = a2;
  }
}

// ---------------- sum rows of [R][128] -> mid[64][128] ----------------
__global__ __launch_bounds__(256) void sumcols128_kernel(const float* __restrict__ partial,
    int rowsPerBlock, float* __restrict__ mid) {
  const int b = blockIdx.x, t = threadIdx.x;
  const int c = t & 127, rh = t >> 7;
  float a = 0.0f;
  for (int r = rh; r < rowsPerBlock; r += 2)
    a += partial[(size_t)(b*rowsPerBlock + r)*128 + c];
  __shared__ float ls[256];
  ls[t] = a;
  __syncthreads();
  if (t < 128) mid[b*128 + t] = ls[t] + ls[t + 128];
}

__global__ __launch_bounds__(256) void stats_final_kernel(const float* __restrict__ partial,
    int G, int C, float invRows,
    const float* __restrict__ gamma, const float* __restrict__ beta,
    float* __restrict__ ss) {
  const int t = threadIdx.x;
  if (t >= C) return;
  float s = 0.0f, s2 = 0.0f;
  for (int g = 0; g < G; ++g) { s += partial[g*2*C + t]; s2 += partial[g*2*C + C + t]; }
  const float mu  = s * invRows;
  const float var = s2 * invRows - mu*mu;
  const float sc  = gamma[t] * rsqrtf(var + 1e-5f);
  ss[t] = sc; ss[C + t] = beta[t] - mu*sc;
}

// ---------------- conv1 layer2 + max: 4 points per block (one wave each) ----------------
__global__ __launch_bounds__(256) void conv1_l2max_kernel(const float* __restrict__ z1,
    const float* __restrict__ ss, const float* __restrict__ W2,
    const float* __restrict__ b2, float* __restrict__ x1) {
  __shared__ float h[4][KNN][64];
  const int wv = threadIdx.x >> 6, t = threadIdx.x & 63;
  const int i = blockIdx.x*4 + wv;
  const float sc = ss[t], sh = ss[64+t];
  #pragma unroll
  for (int k = 0; k < KNN; ++k) {
    const float z = z1[(size_t)(i*KNN+k)*64 + t];
    h[wv][k][t] = fmaxf(z*sc + sh, 0.0f);
  }
  __syncthreads();
  float w[64];
  #pragma unroll
  for (int d = 0; d < 64; ++d) w[d] = W2[d*64 + t];
  const float bb = b2[t];
  float acc = -INFINITY;
  for (int k = 0; k < KNN; ++k) {
    float y = bb;
    #pragma unroll
    for (int d = 0; d < 64; ++d) y += h[wv][k][d]*w[d];
    acc = fmaxf(acc, y);
  }
  x1[(size_t)i*64 + t] = acc;
}

// ---------------- conv2 layer1 + fused BN partials ----------------
__global__ __launch_bounds__(256) void conv2_l1_kernel(const float* __restrict__ x1,
    const int* __restrict__ idx, const float* __restrict__ rel,
    const float* __restrict__ W, const float* __restrict__ bias,
    float* __restrict__ za, float* __restrict__ partial) {
  const int i = blockIdx.x;
  const int t = threadIdx.x;
  const int c = t & 63, kg = t >> 6;
  __shared__ float xg[KNN][64];
  __shared__ float rl[KNN][3];
  __shared__ float ls[256], ls2[256];
  #pragma unroll
  for (int j = 0; j < 4; ++j) {
    const int k = kg + 4*j;
    const int gj = idx[i*KNN + k];
    xg[k][c] = x1[(size_t)gj*64 + c];
  }
  if (t < KNN*3) rl[t/3][t%3] = rel[i*KNN*3 + t];
  __syncthreads();
  float w[67];
  #pragma unroll
  for (int q = 0; q < 67; ++q) w[q] = W[q*64 + c];
  const float bb = bias[c];
  float s = 0.0f, s2 = 0.0f;
  #pragma unroll
  for (int j = 0; j < 4; ++j) {
    const int k = kg + 4*j;
    float y = bb + rl[k][0]*w[64] + rl[k][1]*w[65] + rl[k][2]*w[66];
    #pragma unroll
    for (int q = 0; q < 64; ++q) y += xg[k][q]*w[q];
    za[(size_t)(i*KNN+k)*64 + c] = y;
    s += y; s2 += y*y;
  }
  ls[t] = s; ls2[t] = s2;
  __syncthreads();
  if (t < 64) {
    float a = ls[t] + ls[t+64] + ls[t+128] + ls[t+192];
    float a2 = ls2[t] + ls2[t+64] + ls2[t+128] + ls2[t+192];
    partial[(size_t)i*128 + t]      = a;
    partial[(size_t)i*128 + 64 + t] = a2;
  }
}

// ---------------- W3 -> fp16 transposed [1024][128] ----------------
__global__ __launch_bounds__(256) void w3t_kernel(const float* __restrict__ W3,
                                                  unsigned short* __restrict__ W3T) {
  const int k = blockIdx.x;           // 0..127
  for (int n = threadIdx.x; n < 1024; n += 256)
    W3T[n*128 + k] = f2h(W3[(size_t)k*1024 + n]);
}

// ---------------- W2 -> fp16 transposed [128][64] ----------------
__global__ __launch_bounds__(256) void w2t_kernel(const float* __restrict__ W2,
                                                  unsigned short* __restrict__ W2T) {
  const int id0 = blockIdx.x*256 + threadIdx.x;
  const int stride = gridDim.x * 256;
  for (int id = id0; id < 128*64; id += stride) {
    const int n = id >> 6, k = id & 63;
    W2T[n*64 + k] = f2h(W2[k*128 + n]);
  }
}

// ---------------- conv2 layer2: fp16 MFMA + fused BN-stats; writes zb as fp16 ----------------
__global__ __launch_bounds__(256) void conv2_l2_mfma(
    const float* __restrict__ za, const float* __restrict__ ss,
    const unsigned short* __restrict__ W2T, const float* __restrict__ b2,
    unsigned short* __restrict__ zhb, float* __restrict__ partialB) {
  __shared__ unsigned short S[128*128];   // first 16KB: As; later: fp16 out tile
  __shared__ float ps[512];
  const int r0 = blockIdx.x * 128;
  const int t = threadIdx.x;
  const int lane = t & 63, w = t >> 6;
  const int quad = lane >> 4, mcol = lane & 15;

  // stage A: 128 rows x 64 ch, relu(bn) -> fp16, swizzled
  {
    const int kb = t & 7;
    const int rr = t >> 3;
    float sc[8], sh[8];
    #pragma unroll
    for (int q = 0; q < 8; ++q) { sc[q] = ss[kb*8 + q]; sh[q] = ss[64 + kb*8 + q]; }
    #pragma unroll
    for (int it = 0; it < 4; ++it) {
      const int r = rr + it*32;
      const float* src = za + (size_t)(r0 + r)*64 + kb*8;
      const float4 v0 = *(const float4*)(src);
      const float4 v1 = *(const float4*)(src + 4);
      union { unsigned short s[8]; uint4 v; } o;
      o.s[0] = f2h(fmaxf(v0.x*sc[0] + sh[0], 0.0f));
      o.s[1] = f2h(fmaxf(v0.y*sc[1] + sh[1], 0.0f));
      o.s[2] = f2h(fmaxf(v0.z*sc[2] + sh[2], 0.0f));
      o.s[3] = f2h(fmaxf(v0.w*sc[3] + sh[3], 0.0f));
      o.s[4] = f2h(fmaxf(v1.x*sc[4] + sh[4], 0.0f));
      o.s[5] = f2h(fmaxf(v1.y*sc[5] + sh[5], 0.0f));
      o.s[6] = f2h(fmaxf(v1.z*sc[6] + sh[6], 0.0f));
      o.s[7] = f2h(fmaxf(v1.w*sc[7] + sh[7], 0.0f));
      *(uint4*)(S + r*64 + ((kb ^ (r & 7)) * 8)) = o.v;
    }
  }
  __syncthreads();

  const int wrow = (w >> 1) * 64;
  const int wcol = (w & 1) * 64;

  f16x8 af[2][4], bfr[2][4];
  #pragma unroll
  for (int ks = 0; ks < 2; ++ks)
    #pragma unroll
    for (int mi = 0; mi < 4; ++mi) {
      const int row = wrow + mi*16 + mcol;
      af[ks][mi] = *(const f16x8*)(S + row*64 + (((ks*4 + quad) ^ (row & 7)) * 8));
    }
  #pragma unroll
  for (int ks = 0; ks < 2; ++ks)
    #pragma unroll
    for (int ni = 0; ni < 4; ++ni) {
      const int nr = wcol + ni*16 + mcol;
      bfr[ks][ni] = *(const f16x8*)(W2T + nr*64 + ks*32 + quad*8);
    }

  f32x4 acc[4][4];
  #pragma unroll
  for (int mi = 0; mi < 4; ++mi)
    #pragma unroll
    for (int ni = 0; ni < 4; ++ni)
      acc[mi][ni] = (f32x4){0.f, 0.f, 0.f, 0.f};

  #pragma unroll
  for (int ks = 0; ks < 2; ++ks)
    #pragma unroll
    for (int mi = 0; mi < 4; ++mi)
      #pragma unroll
      for (int ni = 0; ni < 4; ++ni)
        acc[mi][ni] = __builtin_amdgcn_mfma_f32_16x16x32_f16(af[ks][mi], bfr[ks][ni], acc[mi][ni], 0, 0, 0);

  __syncthreads();

  float bb[4];
  #pragma unroll
  for (int ni = 0; ni < 4; ++ni) bb[ni] = b2[wcol + ni*16 + mcol];
  float s[4] = {0,0,0,0}, s2[4] = {0,0,0,0};
  #pragma unroll
  for (int mi = 0; mi < 4; ++mi) {
    #pragma unroll
    for (int ni = 0; ni < 4; ++ni) {
      const int col = wcol + ni*16 + mcol;
      const int g = col >> 3, o = col & 7;
      #pragma unroll
      for (int j = 0; j < 4; ++j) {
        const int row = wrow + mi*16 + quad*4 + j;
        const float v = acc[mi][ni][j] + bb[ni];
        S[row*128 + ((g ^ (row & 15)) << 3) + o] = f2h(v);
        s[ni] += v; s2[ni] += v*v;
      }
    }
  }
  #pragma unroll
  for (int ni = 0; ni < 4; ++ni) {
    s[ni]  += __shfl_xor(s[ni], 16);  s[ni]  += __shfl_xor(s[ni], 32);
    s2[ni] += __shfl_xor(s2[ni], 16); s2[ni] += __shfl_xor(s2[ni], 32);
  }
  if (quad == 0) {
    const int rh = w >> 1;
    #pragma unroll
    for (int ni = 0; ni < 4; ++ni) {
      const int col = wcol + ni*16 + mcol;
      ps[rh*256 + col]       = s[ni];
      ps[rh*256 + 128 + col] = s2[ni];
    }
  }
  __syncthreads();

  #pragma unroll
  for (int i = 0; i < 8; ++i) {
    const int u = i*256 + t;
    const int row = u >> 4, gg = u & 15;
    *(uint4*)(zhb + (size_t)(r0 + row)*128 + gg*8) =
        *(const uint4*)(S + row*128 + ((gg ^ (row & 15)) << 3));
  }
  partialB[(size_t)blockIdx.x*256 + t] = ps[t] + ps[256 + t];
}

// ---------------- sum columns of [1024][256] -> [64][256] ----------------
__global__ __launch_bounds__(256) void sumcols256_kernel(const float* __restrict__ partial,
                                                         float* __restrict__ mid) {
  const int b = blockIdx.x, t = threadIdx.x;
  float a = 0.0f;
  #pragma unroll
  for (int i = 0; i < 16; ++i) a += partial[(size_t)(b*16 + i)*256 + t];
  mid[b*256 + t] = a;
}

// ---------------- conv2 layer3 + max: fp16 MFMA, register-resident output ----------------
// 2048 blocks: rb = bid & 1023 (128 rows), ch = bid >> 10 (512-col half; same XCD as partner).
// A in LDS (32 KB, only LDS use); per chunk B from L2; max kept in regs (quad q holds chunk q).
__global__ __launch_bounds__(256, 4) void conv2_l3max_mfma(
    const unsigned short* __restrict__ zhb, const float* __restrict__ ss,
    const unsigned short* __restrict__ W3T, const float* __restrict__ b3,
    float* __restrict__ x2) {
  __shared__ unsigned short As[128*128];
  const int rb = blockIdx.x & 1023, ch = blockIdx.x >> 10;
  const int r0 = rb * 128;
  const int t = threadIdx.x;
  const int lane = t & 63, w = t >> 6;
  const int quad = lane >> 4, mcol = lane & 15;

  // ---- stage A: relu(bn(zhb)) fp16 -> fp16, swizzled ----
  {
    const int kb = t & 15;
    const int rr = t >> 4;
    float sc[8], sh[8];
    #pragma unroll
    for (int q = 0; q < 8; ++q) { sc[q] = ss[kb*8 + q]; sh[q] = ss[128 + kb*8 + q]; }
    #pragma unroll
    for (int it = 0; it < 8; ++it) {
      const int r = rr + it*16;
      union { uint4 v; unsigned short s[8]; } in;
      in.v = *(const uint4*)(zhb + (size_t)(r0 + r)*128 + kb*8);
      union { unsigned short s[8]; uint4 v; } o;
      #pragma unroll
      for (int q = 0; q < 8; ++q)
        o.s[q] = f2h(fmaxf(h2f(in.s[q])*sc[q] + sh[q], 0.0f));
      *(uint4*)(As + r*128 + ((kb ^ (r & 7)) * 8)) = o.v;
    }
  }
  __syncthreads();

  const int wrow = (w >> 1) * 64;
  const int wcol = (w & 1) * 64;

  // per-lane output columns (chunk encoded by this lane's quad)
  float bcol_b[4]; int bcol[4];
  #pragma unroll
  for (int ni = 0; ni < 4; ++ni) {
    bcol[ni] = ch*512 + quad*128 + wcol + ni*16 + mcol;
    bcol_b[ni] = b3[bcol[ni]];
  }
  float res[4][4];   // [mi][ni]

  #pragma unroll 1
  for (int chunk = 0; chunk < 4; ++chunk) {
    const int n0 = ch*512 + chunk*128;

    f32x4 acc[4][4];
    #pragma unroll
    for (int mi = 0; mi < 4; ++mi)
      #pragma unroll
      for (int ni = 0; ni < 4; ++ni)
        acc[mi][ni] = (f32x4){0.f, 0.f, 0.f, 0.f};

    #pragma unroll
    for (int ks = 0; ks < 4; ++ks) {
      f16x8 bfr[4], af[4];
      #pragma unroll
      for (int ni = 0; ni < 4; ++ni) {
        const int nr = n0 + wcol + ni*16 + mcol;
        bfr[ni] = *(const f16x8*)(W3T + (size_t)nr*128 + ks*32 + quad*8);
      }
      #pragma unroll
      for (int mi = 0; mi < 4; ++mi) {
        const int row = wrow + mi*16 + mcol;
        af[mi] = *(const f16x8*)(As + row*128 + (((ks*4 + quad) ^ (row & 7)) * 8));
      }
      #pragma unroll
      for (int mi = 0; mi < 4; ++mi)
        #pragma unroll
        for (int ni = 0; ni < 4; ++ni)
          acc[mi][ni] = __builtin_amdgcn_mfma_f32_16x16x32_f16(af[mi], bfr[ni], acc[mi][ni], 0, 0, 0);
    }

    // fused max over 16 rows; quad==chunk lanes keep the value
    #pragma unroll
    for (int mi = 0; mi < 4; ++mi) {
      #pragma unroll
      for (int ni = 0; ni < 4; ++ni) {
        f32x4 a = acc[mi][ni];
        float m = fmaxf(fmaxf(a[0], a[1]), fmaxf(a[2], a[3]));
        m = fmaxf(m, __shfl_xor(m, 16));
        m = fmaxf(m, __shfl_xor(m, 32));
        if (quad == chunk) res[mi][ni] = m;
      }
    }
  }

  // final stores: 16 per lane, 64B-coalesced within quads
  #pragma unroll
  for (int mi = 0; mi < 4; ++mi) {
    const int p = rb*8 + (w >> 1)*4 + mi;
    #pragma unroll
    for (int ni = 0; ni < 4; ++ni)
      x2[(size_t)p*1024 + bcol[ni]] = res[mi][ni] + bcol_b[ni];
  }
}

// ---------------- global max pool, two coalesced stages ----------------
__global__ __launch_bounds__(256) void pool1_kernel(const float* __restrict__ x2,
                                                    float* __restrict__ pmax) {
  const int b = blockIdx.x >> 6, g = blockIdx.x & 63;
  const int t = threadIdx.x;
  const float* base = x2 + (size_t)(b*1024 + g*16)*1024;
  float m0 = -INFINITY, m1 = -INFINITY, m2 = -INFINITY, m3 = -INFINITY;
  for (int n = 0; n < 16; ++n) {
    const float* row = base + (size_t)n*1024;
    m0 = fmaxf(m0, row[t]);
    m1 = fmaxf(m1, row[t + 256]);
    m2 = fmaxf(m2, row[t + 512]);
    m3 = fmaxf(m3, row[t + 768]);
  }
  float* o = pmax + (size_t)blockIdx.x*1024;
  o[t] = m0; o[t+256] = m1; o[t+512] = m2; o[t+768] = m3;
}

__global__ __launch_bounds__(256) void pool2_kernel(const float* __restrict__ pmax,
                                                    float* __restrict__ g) {
  const int id = blockIdx.x*256 + threadIdx.x; // b*1024 + c
  const int b = id >> 10, c = id & 1023;
  float m = -INFINITY;
  for (int q = 0; q < 64; ++q) m = fmaxf(m, pmax[(size_t)(b*64 + q)*1024 + c]);
  g[id] = m;
}

// ---------------- final linear (partials over c-quarters) ----------------
__global__ __launch_bounds__(256) void lin_kernel(const float* __restrict__ g,
    const float* __restrict__ W, float* __restrict__ zpart) {
  const int b = blockIdx.x >> 2, q = blockIdx.x & 3;
  const int o = threadIdx.x;
  const float* gb = g + b*1024 + q*256;
  const float* Wq = W + q*256*256;
  float acc = 0.0f;
  for (int c = 0; c < 256; ++c) acc += gb[c] * Wq[c*256 + o];
  zpart[blockIdx.x*256 + o] = acc;
}

// ---------------- final BN(8 rows) + relu ----------------
__global__ __launch_bounds__(256) void final_kernel(const float* __restrict__ zpart,
    const float* __restrict__ lb, const float* __restrict__ lg,
    const float* __restrict__ lbe, float* __restrict__ out) {
  const int o = threadIdx.x;
  float z[NB]; float s = 0.0f, s2 = 0.0f;
  #pragma unroll
  for (int b = 0; b < NB; ++b) {
    float v = lb[o];
    #pragma unroll
    for (int q = 0; q < 4; ++q) v += zpart[(b*4+q)*256 + o];
    z[b] = v; s += v; s2 += v*v;
  }
  const float mu  = s * 0.125f;
  const float var = s2 * 0.125f - mu*mu;
  const float inv = rsqrtf(var + 1e-5f);
  const float sc = lg[o]*inv, sh = lbe[o] - mu*sc;
  #pragma unroll
  for (int b = 0; b < NB; ++b) out[b*256 + o] = fmaxf(z[b]*sc + sh, 0.0f);
}

extern "C" void kernel_launch(void* const* d_in, const int* in_sizes, int n_in,
                              void* d_out, int out_size, void* d_ws, size_t ws_size,
                              hipStream_t stream) {
  const float* pos    = (const float*)d_in[0];
  const float* c1_W1  = (const float*)d_in[2];
  const float* c1_b1  = (const float*)d_in[3];
  const float* c1_g1  = (const float*)d_in[4];
  const float* c1_be1 = (const float*)d_in[5];
  const float* c1_W2  = (const float*)d_in[6];
  const float* c1_b2  = (const float*)d_in[7];
  const float* c2_W1  = (const float*)d_in[8];
  const float* c2_b1  = (const float*)d_in[9];
  const float* c2_g1  = (const float*)d_in[10];
  const float* c2_be1 = (const float*)d_in[11];
  const float* c2_W2  = (const float*)d_in[12];
  const float* c2_b2  = (const float*)d_in[13];
  const float* c2_g2  = (const float*)d_in[14];
  const float* c2_be2 = (const float*)d_in[15];
  const float* c2_W3  = (const float*)d_in[16];
  const float* c2_b3  = (const float*)d_in[17];
  const float* lin_W  = (const float*)d_in[18];
  const float* lin_b  = (const float*)d_in[19];
  const float* lin_g  = (const float*)d_in[20];
  const float* lin_be = (const float*)d_in[21];
  float* out = (float*)d_out;

  char* ws = (char*)d_ws;
  int*   idx     = (int*)  (ws + 0);                 // 512 KB
  float* rel     = (float*)(ws + 524288);            // 1.5 MB
  float* ss1     = (float*)(ws + 2097152);           // 128
  float* ssA     = (float*)(ws + 2097152 + 512);     // 128
  float* ssB     = (float*)(ws + 2097152 + 1024);    // 256
  float* zpart   = (float*)(ws + 2097152 + 2048);    // 8192
  float* gpool   = (float*)(ws + 2097152 + 2048 + 32768);          // 8192
  float* mid     = (float*)(ws + 2097152 + 2048 + 65536);          // 64 x 128 (32 KB)
  float* midB    = (float*)(ws + 2097152 + 2048 + 65536 + 32768);  // 64 x 256 (64 KB)
  unsigned short* W2T = (unsigned short*)(ws + 2164736 + 131072);  // 16 KB
  float* bufA    = (float*)(ws + 2426880);           // 33.5 MB (z1 / za / x2)
  float* x1      = (float*)(ws + 35981312);          // 2 MB (x1, then W3T)
  unsigned short* W3T = (unsigned short*)(ws + 35981312);
  unsigned short* zhb = (unsigned short*)(ws + 38078464);  // 33.5 MB: conv1/conv2_l1 partials, then fp16 zb, then pmax
  float* partialP= (float*)(ws + 38078464);                // partials for conv1_l1 (1 MB) / conv2_l1 (4 MB)
  float* pmax    = (float*)(ws + 38078464);                // 2 MB (after l3max consumed zhb)
  float* partialB= (float*)(ws + 71632896);          // 1 MB  (1024 x 256)

  const float invPK = 1.0f / (float)PK;

  knn_kernel<<<PTS/4, 256, 0, stream>>>(pos, idx, rel);
  conv1_l1_kernel<<<PK/64, 256, 0, stream>>>(pos, idx, rel, c1_W1, c1_b1, bufA, partialP);
  sumcols128_kernel<<<64, 256, 0, stream>>>(partialP, 32, mid);
  stats_final_kernel<<<1, 256, 0, stream>>>(mid, 64, 64, invPK, c1_g1, c1_be1, ss1);
  conv1_l2max_kernel<<<PTS/4, 256, 0, stream>>>(bufA, ss1, c1_W2, c1_b2, x1);
  conv2_l1_kernel<<<PTS, 256, 0, stream>>>(x1, idx, rel, c2_W1, c2_b1, bufA, partialP);
  w3t_kernel<<<128, 256, 0, stream>>>(c2_W3, W3T);
  w2t_kernel<<<8, 256, 0, stream>>>(c2_W2, W2T);
  sumcols128_kernel<<<64, 256, 0, stream>>>(partialP, 128, mid);
  stats_final_kernel<<<1, 256, 0, stream>>>(mid, 64, 64, invPK, c2_g1, c2_be1, ssA);
  conv2_l2_mfma<<<PK/128, 256, 0, stream>>>(bufA, ssA, W2T, c2_b2, zhb, partialB);
  sumcols256_kernel<<<64, 256, 0, stream>>>(partialB, midB);
  stats_final_kernel<<<1, 256, 0, stream>>>(midB, 64, 128, invPK, c2_g2, c2_be2, ssB);
  conv2_l3max_mfma<<<PK/64, 256, 0, stream>>>(zhb, ssB, W3T, c2_b3, bufA);
  pool1_kernel<<<NB*64, 256, 0, stream>>>(bufA, pmax);
  pool2_kernel<<<PTS/256, 256, 0, stream>>>(pmax, gpool);
  lin_kernel<<<32, 256, 0, stream>>>(gpool, lin_W, zpart);
  final_kernel<<<1, 256, 0, stream>>>(zpart, lin_b, lin_g, lin_be, out);
}

// Round 10
// 415.292 us; speedup vs baseline: 1.6977x; 1.2242x over previous
//
#include <hip/hip_runtime.h>
#include <math.h>

#define NB   8
#define NPTS 1024
#define PTS  8192      // NB*NPTS
#define KNN  16
#define PK   (PTS*KNN) // 131072

typedef __attribute__((ext_vector_type(8))) _Float16 f16x8;
typedef __attribute__((ext_vector_type(4))) float f32x4;

__device__ __forceinline__ unsigned short f2h(float f) {
  _Float16 h = (_Float16)f;
  union { _Float16 h; unsigned short u; } c; c.h = h;
  return c.u;
}
__device__ __forceinline__ float h2f(unsigned short u) {
  union { unsigned short u; _Float16 h; } c; c.u = u;
  return (float)c.h;
}

// ---------------- kNN: one WAVE per point; register-resident top-16, barrier-free ----------------
__global__ __launch_bounds__(256) void knn_kernel(const float* __restrict__ pos,
                                                  int* __restrict__ idx,
                                                  float* __restrict__ rel) {
  __shared__ float px[NPTS], py[NPTS], pz[NPTS];
  const int t = threadIdx.x;
  const int wv = t >> 6, lane = t & 63;
  const int b = blockIdx.x;
  const int graph = b >> 8;             // 256 blocks per graph
  const int base = graph << 10;
  for (int j = t; j < NPTS; j += 256) {
    px[j] = pos[3*(base+j)];
    py[j] = pos[3*(base+j)+1];
    pz[j] = pos[3*(base+j)+2];
  }
  __syncthreads();

  const int il = ((b & 255) << 2) + wv; // point index within graph
  const float pix = px[il], piy = py[il], piz = pz[il];
  const float sqi = pix*pix + piy*piy + piz*piz;

  float d[16];
  #pragma unroll
  for (int q = 0; q < 16; ++q) {
    const int j = (q << 6) + lane;
    const float x = px[j], y = py[j], z = pz[j];
    const float sqj = x*x + y*y + z*z;
    const float dt  = pix*x + piy*y + piz*z;
    d[q] = sqi + sqj - 2.0f*dt;
  }
  float mv = d[0]; int mq = 0;
  #pragma unroll
  for (int q = 1; q < 16; ++q) { if (d[q] < mv) { mv = d[q]; mq = q; } }

  int sel = 0;
  for (int s = 0; s < KNN; ++s) {
    float v = mv; int j = (mq << 6) + lane;
    #pragma unroll
    for (int m = 1; m <= 32; m <<= 1) {
      const float v2 = __shfl_xor(v, m);
      const int   j2 = __shfl_xor(j, m);
      if (v2 < v || (v2 == v && j2 < j)) { v = v2; j = j2; }
    }
    if (lane == s) sel = j;
    if (lane == (j & 63)) {
      const int wq = j >> 6;
      #pragma unroll
      for (int q = 0; q < 16; ++q) if (q == wq) d[q] = INFINITY;
      mv = d[0]; mq = 0;
      #pragma unroll
      for (int q = 1; q < 16; ++q) { if (d[q] < mv) { mv = d[q]; mq = q; } }
    }
  }

  if (lane < KNN) {
    const int i = base + il;
    const int r = i*KNN + lane;
    idx[r] = base + sel;
    rel[3*r]   = px[sel] - pix;
    rel[3*r+1] = py[sel] - piy;
    rel[3*r+2] = pz[sel] - piz;
  }
}

// ---------------- conv1 layer1 + fused BN partials ----------------
__global__ __launch_bounds__(256) void conv1_l1_kernel(const float* __restrict__ pos,
    const int* __restrict__ idx, const float* __restrict__ rel,
    const float* __restrict__ W1, const float* __restrict__ b1,
    float* __restrict__ z1, float* __restrict__ partial) {
  const int r0 = blockIdx.x * 64;
  const int t = threadIdx.x;
  __shared__ float f[64][6];
  __shared__ float ls[256], ls2[256];
  if (t < 64) {
    const int r = r0 + t;
    const int j = idx[r];
    f[t][0] = pos[3*j]; f[t][1] = pos[3*j+1]; f[t][2] = pos[3*j+2];
    f[t][3] = rel[3*r]; f[t][4] = rel[3*r+1]; f[t][5] = rel[3*r+2];
  }
  __syncthreads();
  const int c = t & 63, rg = t >> 6;
  float w[6];
  #pragma unroll
  for (int q = 0; q < 6; ++q) w[q] = W1[q*64 + c];
  const float bb = b1[c];
  float s = 0.0f, s2 = 0.0f;
  for (int j = 0; j < 16; ++j) {
    const int lr = rg + 4*j;
    float z = bb;
    #pragma unroll
    for (int q = 0; q < 6; ++q) z += f[lr][q]*w[q];
    z1[(size_t)(r0+lr)*64 + c] = z;
    s += z; s2 += z*z;
  }
  ls[t] = s; ls2[t] = s2;
  __syncthreads();
  if (t < 64) {
    float a = ls[t] + ls[t+64] + ls[t+128] + ls[t+192];
    float a2 = ls2[t] + ls2[t+64] + ls2[t+128] + ls2[t+192];
    partial[(size_t)blockIdx.x*128 + t]      = a;
    partial[(size_t)blockIdx.x*128 + 64 + t] = a2;
  }
}

// ---------------- sum rows of [R][128] -> mid[64][128] ----------------
__global__ __launch_bounds__(256) void sumcols128_kernel(const float* __restrict__ partial,
    int rowsPerBlock, float* __restrict__ mid) {
  const int b = blockIdx.x, t = threadIdx.x;
  const int c = t & 127, rh = t >> 7;
  float a = 0.0f;
  for (int r = rh; r < rowsPerBlock; r += 2)
    a += partial[(size_t)(b*rowsPerBlock + r)*128 + c];
  __shared__ float ls[256];
  ls[t] = a;
  __syncthreads();
  if (t < 128) mid[b*128 + t] = ls[t] + ls[t + 128];
}

__global__ __launch_bounds__(256) void stats_final_kernel(const float* __restrict__ partial,
    int G, int C, float invRows,
    const float* __restrict__ gamma, const float* __restrict__ beta,
    float* __restrict__ ss) {
  const int t = threadIdx.x;
  if (t >= C) return;
  float s = 0.0f, s2 = 0.0f;
  for (int g = 0; g < G; ++g) { s += partial[g*2*C + t]; s2 += partial[g*2*C + C + t]; }
  const float mu  = s * invRows;
  const float var = s2 * invRows - mu*mu;
  const float sc  = gamma[t] * rsqrtf(var + 1e-5f);
  ss[t] = sc; ss[C + t] = beta[t] - mu*sc;
}

// ---------------- conv1 layer2 + max: 4 points per block (one wave each) ----------------
__global__ __launch_bounds__(256) void conv1_l2max_kernel(const float* __restrict__ z1,
    const float* __restrict__ ss, const float* __restrict__ W2,
    const float* __restrict__ b2, float* __restrict__ x1) {
  __shared__ float h[4][KNN][64];
  const int wv = threadIdx.x >> 6, t = threadIdx.x & 63;
  const int i = blockIdx.x*4 + wv;
  const float sc = ss[t], sh = ss[64+t];
  #pragma unroll
  for (int k = 0; k < KNN; ++k) {
    const float z = z1[(size_t)(i*KNN+k)*64 + t];
    h[wv][k][t] = fmaxf(z*sc + sh, 0.0f);
  }
  __syncthreads();
  float w[64];
  #pragma unroll
  for (int d = 0; d < 64; ++d) w[d] = W2[d*64 + t];
  const float bb = b2[t];
  float acc = -INFINITY;
  for (int k = 0; k < KNN; ++k) {
    float y = bb;
    #pragma unroll
    for (int d = 0; d < 64; ++d) y += h[wv][k][d]*w[d];
    acc = fmaxf(acc, y);
  }
  x1[(size_t)i*64 + t] = acc;
}

// ---------------- conv2 layer1 + fused BN partials ----------------
__global__ __launch_bounds__(256) void conv2_l1_kernel(const float* __restrict__ x1,
    const int* __restrict__ idx, const float* __restrict__ rel,
    const float* __restrict__ W, const float* __restrict__ bias,
    float* __restrict__ za, float* __restrict__ partial) {
  const int i = blockIdx.x;
  const int t = threadIdx.x;
  const int c = t & 63, kg = t >> 6;
  __shared__ float xg[KNN][64];
  __shared__ float rl[KNN][3];
  __shared__ float ls[256], ls2[256];
  #pragma unroll
  for (int j = 0; j < 4; ++j) {
    const int k = kg + 4*j;
    const int gj = idx[i*KNN + k];
    xg[k][c] = x1[(size_t)gj*64 + c];
  }
  if (t < KNN*3) rl[t/3][t%3] = rel[i*KNN*3 + t];
  __syncthreads();
  float w[67];
  #pragma unroll
  for (int q = 0; q < 67; ++q) w[q] = W[q*64 + c];
  const float bb = bias[c];
  float s = 0.0f, s2 = 0.0f;
  #pragma unroll
  for (int j = 0; j < 4; ++j) {
    const int k = kg + 4*j;
    float y = bb + rl[k][0]*w[64] + rl[k][1]*w[65] + rl[k][2]*w[66];
    #pragma unroll
    for (int q = 0; q < 64; ++q) y += xg[k][q]*w[q];
    za[(size_t)(i*KNN+k)*64 + c] = y;
    s += y; s2 += y*y;
  }
  ls[t] = s; ls2[t] = s2;
  __syncthreads();
  if (t < 64) {
    float a = ls[t] + ls[t+64] + ls[t+128] + ls[t+192];
    float a2 = ls2[t] + ls2[t+64] + ls2[t+128] + ls2[t+192];
    partial[(size_t)i*128 + t]      = a;
    partial[(size_t)i*128 + 64 + t] = a2;
  }
}

// ---------------- W3 -> fp16 transposed [1024][128] ----------------
__global__ __launch_bounds__(256) void w3t_kernel(const float* __restrict__ W3,
                                                  unsigned short* __restrict__ W3T) {
  const int k = blockIdx.x;           // 0..127
  for (int n = threadIdx.x; n < 1024; n += 256)
    W3T[n*128 + k] = f2h(W3[(size_t)k*1024 + n]);
}

// ---------------- W2 -> fp16 transposed [128][64] ----------------
__global__ __launch_bounds__(256) void w2t_kernel(const float* __restrict__ W2,
                                                  unsigned short* __restrict__ W2T) {
  const int id0 = blockIdx.x*256 + threadIdx.x;
  const int stride = gridDim.x * 256;
  for (int id = id0; id < 128*64; id += stride) {
    const int n = id >> 6, k = id & 63;
    W2T[n*64 + k] = f2h(W2[k*128 + n]);
  }
}

// ---------------- conv2 layer2: fp16 MFMA + fused BN-stats; writes zb as fp16 ----------------
__global__ __launch_bounds__(256) void conv2_l2_mfma(
    const float* __restrict__ za, const float* __restrict__ ss,
    const unsigned short* __restrict__ W2T, const float* __restrict__ b2,
    unsigned short* __restrict__ zhb, float* __restrict__ partialB) {
  __shared__ unsigned short S[128*128];   // first 16KB: As; later: fp16 out tile
  __shared__ float ps[512];
  const int r0 = blockIdx.x * 128;
  const int t = threadIdx.x;
  const int lane = t & 63, w = t >> 6;
  const int quad = lane >> 4, mcol = lane & 15;

  // stage A: 128 rows x 64 ch, relu(bn) -> fp16, swizzled
  {
    const int kb = t & 7;
    const int rr = t >> 3;
    float sc[8], sh[8];
    #pragma unroll
    for (int q = 0; q < 8; ++q) { sc[q] = ss[kb*8 + q]; sh[q] = ss[64 + kb*8 + q]; }
    #pragma unroll
    for (int it = 0; it < 4; ++it) {
      const int r = rr + it*32;
      const float* src = za + (size_t)(r0 + r)*64 + kb*8;
      const float4 v0 = *(const float4*)(src);
      const float4 v1 = *(const float4*)(src + 4);
      union { unsigned short s[8]; uint4 v; } o;
      o.s[0] = f2h(fmaxf(v0.x*sc[0] + sh[0], 0.0f));
      o.s[1] = f2h(fmaxf(v0.y*sc[1] + sh[1], 0.0f));
      o.s[2] = f2h(fmaxf(v0.z*sc[2] + sh[2], 0.0f));
      o.s[3] = f2h(fmaxf(v0.w*sc[3] + sh[3], 0.0f));
      o.s[4] = f2h(fmaxf(v1.x*sc[4] + sh[4], 0.0f));
      o.s[5] = f2h(fmaxf(v1.y*sc[5] + sh[5], 0.0f));
      o.s[6] = f2h(fmaxf(v1.z*sc[6] + sh[6], 0.0f));
      o.s[7] = f2h(fmaxf(v1.w*sc[7] + sh[7], 0.0f));
      *(uint4*)(S + r*64 + ((kb ^ (r & 7)) * 8)) = o.v;
    }
  }
  __syncthreads();

  const int wrow = (w >> 1) * 64;
  const int wcol = (w & 1) * 64;

  f16x8 af[2][4], bfr[2][4];
  #pragma unroll
  for (int ks = 0; ks < 2; ++ks)
    #pragma unroll
    for (int mi = 0; mi < 4; ++mi) {
      const int row = wrow + mi*16 + mcol;
      af[ks][mi] = *(const f16x8*)(S + row*64 + (((ks*4 + quad) ^ (row & 7)) * 8));
    }
  #pragma unroll
  for (int ks = 0; ks < 2; ++ks)
    #pragma unroll
    for (int ni = 0; ni < 4; ++ni) {
      const int nr = wcol + ni*16 + mcol;
      bfr[ks][ni] = *(const f16x8*)(W2T + nr*64 + ks*32 + quad*8);
    }

  f32x4 acc[4][4];
  #pragma unroll
  for (int mi = 0; mi < 4; ++mi)
    #pragma unroll
    for (int ni = 0; ni < 4; ++ni)
      acc[mi][ni] = (f32x4){0.f, 0.f, 0.f, 0.f};

  #pragma unroll
  for (int ks = 0; ks < 2; ++ks)
    #pragma unroll
    for (int mi = 0; mi < 4; ++mi)
      #pragma unroll
      for (int ni = 0; ni < 4; ++ni)
        acc[mi][ni] = __builtin_amdgcn_mfma_f32_16x16x32_f16(af[ks][mi], bfr[ks][ni], acc[mi][ni], 0, 0, 0);

  __syncthreads();

  float bb[4];
  #pragma unroll
  for (int ni = 0; ni < 4; ++ni) bb[ni] = b2[wcol + ni*16 + mcol];
  float s[4] = {0,0,0,0}, s2[4] = {0,0,0,0};
  #pragma unroll
  for (int mi = 0; mi < 4; ++mi) {
    #pragma unroll
    for (int ni = 0; ni < 4; ++ni) {
      const int col = wcol + ni*16 + mcol;
      const int g = col >> 3, o = col & 7;
      #pragma unroll
      for (int j = 0; j < 4; ++j) {
        const int row = wrow + mi*16 + quad*4 + j;
        const float v = acc[mi][ni][j] + bb[ni];
        S[row*128 + ((g ^ (row & 15)) << 3) + o] = f2h(v);
        s[ni] += v; s2[ni] += v*v;
      }
    }
  }
  #pragma unroll
  for (int ni = 0; ni < 4; ++ni) {
    s[ni]  += __shfl_xor(s[ni], 16);  s[ni]  += __shfl_xor(s[ni], 32);
    s2[ni] += __shfl_xor(s2[ni], 16); s2[ni] += __shfl_xor(s2[ni], 32);
  }
  if (quad == 0) {
    const int rh = w >> 1;
    #pragma unroll
    for (int ni = 0; ni < 4; ++ni) {
      const int col = wcol + ni*16 + mcol;
      ps[rh*256 + col]       = s[ni];
      ps[rh*256 + 128 + col] = s2[ni];
    }
  }
  __syncthreads();

  #pragma unroll
  for (int i = 0; i < 8; ++i) {
    const int u = i*256 + t;
    const int row = u >> 4, gg = u & 15;
    *(uint4*)(zhb + (size_t)(r0 + row)*128 + gg*8) =
        *(const uint4*)(S + row*128 + ((gg ^ (row & 15)) << 3));
  }
  partialB[(size_t)blockIdx.x*256 + t] = ps[t] + ps[256 + t];
}

// ---------------- sum columns of [1024][256] -> [64][256] ----------------
__global__ __launch_bounds__(256) void sumcols256_kernel(const float* __restrict__ partial,
                                                         float* __restrict__ mid) {
  const int b = blockIdx.x, t = threadIdx.x;
  float a = 0.0f;
  #pragma unroll
  for (int i = 0; i < 16; ++i) a += partial[(size_t)(b*16 + i)*256 + t];
  mid[b*256 + t] = a;
}

// ---------------- conv2 layer3 + max: fp16 MFMA, register-resident output ----------------
// 2048 blocks: rb = bid & 1023 (128 rows), ch = bid >> 10 (512-col half; same XCD as partner).
// A in LDS (32 KB only); per-chunk B from L2; max kept in regs (quad q holds chunk q).
// launch_bounds(256,2): cap 256 VGPRs -> NO SPILL (round 9's (256,4) forced VGPR=64 and
// spilled ~0.5 GB to scratch). Expected alloc ~150 -> 3 blocks/CU anyway.
__global__ __launch_bounds__(256, 2) void conv2_l3max_mfma(
    const unsigned short* __restrict__ zhb, const float* __restrict__ ss,
    const unsigned short* __restrict__ W3T, const float* __restrict__ b3,
    float* __restrict__ x2) {
  __shared__ unsigned short As[128*128];
  const int rb = blockIdx.x & 1023, ch = blockIdx.x >> 10;
  const int r0 = rb * 128;
  const int t = threadIdx.x;
  const int lane = t & 63, w = t >> 6;
  const int quad = lane >> 4, mcol = lane & 15;

  // ---- stage A: relu(bn(zhb)) fp16 -> fp16, swizzled ----
  {
    const int kb = t & 15;
    const int rr = t >> 4;
    float sc[8], sh[8];
    #pragma unroll
    for (int q = 0; q < 8; ++q) { sc[q] = ss[kb*8 + q]; sh[q] = ss[128 + kb*8 + q]; }
    #pragma unroll
    for (int it = 0; it < 8; ++it) {
      const int r = rr + it*16;
      union { uint4 v; unsigned short s[8]; } in;
      in.v = *(const uint4*)(zhb + (size_t)(r0 + r)*128 + kb*8);
      union { unsigned short s[8]; uint4 v; } o;
      #pragma unroll
      for (int q = 0; q < 8; ++q)
        o.s[q] = f2h(fmaxf(h2f(in.s[q])*sc[q] + sh[q], 0.0f));
      *(uint4*)(As + r*128 + ((kb ^ (r & 7)) * 8)) = o.v;
    }
  }
  __syncthreads();

  const int wrow = (w >> 1) * 64;
  const int wcol = (w & 1) * 64;

  // per-lane output columns (chunk encoded by this lane's quad)
  float bcol_b[4]; int bcol[4];
  #pragma unroll
  for (int ni = 0; ni < 4; ++ni) {
    bcol[ni] = ch*512 + quad*128 + wcol + ni*16 + mcol;
    bcol_b[ni] = b3[bcol[ni]];
  }
  float res[4][4];   // [mi][ni]

  #pragma unroll 1
  for (int chunk = 0; chunk < 4; ++chunk) {
    const int n0 = ch*512 + chunk*128;

    f32x4 acc[4][4];
    #pragma unroll
    for (int mi = 0; mi < 4; ++mi)
      #pragma unroll
      for (int ni = 0; ni < 4; ++ni)
        acc[mi][ni] = (f32x4){0.f, 0.f, 0.f, 0.f};

    #pragma unroll
    for (int ks = 0; ks < 4; ++ks) {
      f16x8 bfr[4], af[4];
      #pragma unroll
      for (int ni = 0; ni < 4; ++ni) {
        const int nr = n0 + wcol + ni*16 + mcol;
        bfr[ni] = *(const f16x8*)(W3T + (size_t)nr*128 + ks*32 + quad*8);
      }
      #pragma unroll
      for (int mi = 0; mi < 4; ++mi) {
        const int row = wrow + mi*16 + mcol;
        af[mi] = *(const f16x8*)(As + row*128 + (((ks*4 + quad) ^ (row & 7)) * 8));
      }
      #pragma unroll
      for (int mi = 0; mi < 4; ++mi)
        #pragma unroll
        for (int ni = 0; ni < 4; ++ni)
          acc[mi][ni] = __builtin_amdgcn_mfma_f32_16x16x32_f16(af[mi], bfr[ni], acc[mi][ni], 0, 0, 0);
    }

    // fused max over 16 rows; quad==chunk lanes keep the value
    #pragma unroll
    for (int mi = 0; mi < 4; ++mi) {
      #pragma unroll
      for (int ni = 0; ni < 4; ++ni) {
        f32x4 a = acc[mi][ni];
        float m = fmaxf(fmaxf(a[0], a[1]), fmaxf(a[2], a[3]));
        m = fmaxf(m, __shfl_xor(m, 16));
        m = fmaxf(m, __shfl_xor(m, 32));
        if (quad == chunk) res[mi][ni] = m;
      }
    }
  }

  // final stores: 16 per lane, 64B-coalesced within quads
  #pragma unroll
  for (int mi = 0; mi < 4; ++mi) {
    const int p = rb*8 + (w >> 1)*4 + mi;
    #pragma unroll
    for (int ni = 0; ni < 4; ++ni)
      x2[(size_t)p*1024 + bcol[ni]] = res[mi][ni] + bcol_b[ni];
  }
}

// ---------------- global max pool, two coalesced stages ----------------
__global__ __launch_bounds__(256) void pool1_kernel(const float* __restrict__ x2,
                                                    float* __restrict__ pmax) {
  const int b = blockIdx.x >> 6, g = blockIdx.x & 63;
  const int t = threadIdx.x;
  const float* base = x2 + (size_t)(b*1024 + g*16)*1024;
  float m0 = -INFINITY, m1 = -INFINITY, m2 = -INFINITY, m3 = -INFINITY;
  for (int n = 0; n < 16; ++n) {
    const float* row = base + (size_t)n*1024;
    m0 = fmaxf(m0, row[t]);
    m1 = fmaxf(m1, row[t + 256]);
    m2 = fmaxf(m2, row[t + 512]);
    m3 = fmaxf(m3, row[t + 768]);
  }
  float* o = pmax + (size_t)blockIdx.x*1024;
  o[t] = m0; o[t+256] = m1; o[t+512] = m2; o[t+768] = m3;
}

__global__ __launch_bounds__(256) void pool2_kernel(const float* __restrict__ pmax,
                                                    float* __restrict__ g) {
  const int id = blockIdx.x*256 + threadIdx.x; // b*1024 + c
  const int b = id >> 10, c = id & 1023;
  float m = -INFINITY;
  for (int q = 0; q < 64; ++q) m = fmaxf(m, pmax[(size_t)(b*64 + q)*1024 + c]);
  g[id] = m;
}

// ---------------- final linear (partials over c-quarters) ----------------
__global__ __launch_bounds__(256) void lin_kernel(const float* __restrict__ g,
    const float* __restrict__ W, float* __restrict__ zpart) {
  const int b = blockIdx.x >> 2, q = blockIdx.x & 3;
  const int o = threadIdx.x;
  const float* gb = g + b*1024 + q*256;
  const float* Wq = W + q*256*256;
  float acc = 0.0f;
  for (int c = 0; c < 256; ++c) acc += gb[c] * Wq[c*256 + o];
  zpart[blockIdx.x*256 + o] = acc;
}

// ---------------- final BN(8 rows) + relu ----------------
__global__ __launch_bounds__(256) void final_kernel(const float* __restrict__ zpart,
    const float* __restrict__ lb, const float* __restrict__ lg,
    const float* __restrict__ lbe, float* __restrict__ out) {
  const int o = threadIdx.x;
  float z[NB]; float s = 0.0f, s2 = 0.0f;
  #pragma unroll
  for (int b = 0; b < NB; ++b) {
    float v = lb[o];
    #pragma unroll
    for (int q = 0; q < 4; ++q) v += zpart[(b*4+q)*256 + o];
    z[b] = v; s += v; s2 += v*v;
  }
  const float mu  = s * 0.125f;
  const float var = s2 * 0.125f - mu*mu;
  const float inv = rsqrtf(var + 1e-5f);
  const float sc = lg[o]*inv, sh = lbe[o] - mu*sc;
  #pragma unroll
  for (int b = 0; b < NB; ++b) out[b*256 + o] = fmaxf(z[b]*sc + sh, 0.0f);
}

extern "C" void kernel_launch(void* const* d_in, const int* in_sizes, int n_in,
                              void* d_out, int out_size, void* d_ws, size_t ws_size,
                              hipStream_t stream) {
  const float* pos    = (const float*)d_in[0];
  const float* c1_W1  = (const float*)d_in[2];
  const float* c1_b1  = (const float*)d_in[3];
  const float* c1_g1  = (const float*)d_in[4];
  const float* c1_be1 = (const float*)d_in[5];
  const float* c1_W2  = (const float*)d_in[6];
  const float* c1_b2  = (const float*)d_in[7];
  const float* c2_W1  = (const float*)d_in[8];
  const float* c2_b1  = (const float*)d_in[9];
  const float* c2_g1  = (const float*)d_in[10];
  const float* c2_be1 = (const float*)d_in[11];
  const float* c2_W2  = (const float*)d_in[12];
  const float* c2_b2  = (const float*)d_in[13];
  const float* c2_g2  = (const float*)d_in[14];
  const float* c2_be2 = (const float*)d_in[15];
  const float* c2_W3  = (const float*)d_in[16];
  const float* c2_b3  = (const float*)d_in[17];
  const float* lin_W  = (const float*)d_in[18];
  const float* lin_b  = (const float*)d_in[19];
  const float* lin_g  = (const float*)d_in[20];
  const float* lin_be = (const float*)d_in[21];
  float* out = (float*)d_out;

  char* ws = (char*)d_ws;
  int*   idx     = (int*)  (ws + 0);                 // 512 KB
  float* rel     = (float*)(ws + 524288);            // 1.5 MB
  float* ss1     = (float*)(ws + 2097152);           // 128
  float* ssA     = (float*)(ws + 2097152 + 512);     // 128
  float* ssB     = (float*)(ws + 2097152 + 1024);    // 256
  float* zpart   = (float*)(ws + 2097152 + 2048);    // 8192
  float* gpool   = (float*)(ws + 2097152 + 2048 + 32768);          // 8192
  float* mid     = (float*)(ws + 2097152 + 2048 + 65536);          // 64 x 128 (32 KB)
  float* midB    = (float*)(ws + 2097152 + 2048 + 65536 + 32768);  // 64 x 256 (64 KB)
  unsigned short* W2T = (unsigned short*)(ws + 2164736 + 131072);  // 16 KB
  float* bufA    = (float*)(ws + 2426880);           // 33.5 MB (z1 / za / x2)
  float* x1      = (float*)(ws + 35981312);          // 2 MB (x1, then W3T)
  unsigned short* W3T = (unsigned short*)(ws + 35981312);
  unsigned short* zhb = (unsigned short*)(ws + 38078464);  // 33.5 MB: partials, then fp16 zb, then pmax
  float* partialP= (float*)(ws + 38078464);                // partials for conv1_l1 / conv2_l1
  float* pmax    = (float*)(ws + 38078464);                // 2 MB (after l3max consumed zhb)
  float* partialB= (float*)(ws + 71632896);          // 1 MB  (1024 x 256)

  const float invPK = 1.0f / (float)PK;

  knn_kernel<<<PTS/4, 256, 0, stream>>>(pos, idx, rel);
  conv1_l1_kernel<<<PK/64, 256, 0, stream>>>(pos, idx, rel, c1_W1, c1_b1, bufA, partialP);
  sumcols128_kernel<<<64, 256, 0, stream>>>(partialP, 32, mid);
  stats_final_kernel<<<1, 256, 0, stream>>>(mid, 64, 64, invPK, c1_g1, c1_be1, ss1);
  conv1_l2max_kernel<<<PTS/4, 256, 0, stream>>>(bufA, ss1, c1_W2, c1_b2, x1);
  conv2_l1_kernel<<<PTS, 256, 0, stream>>>(x1, idx, rel, c2_W1, c2_b1, bufA, partialP);
  w3t_kernel<<<128, 256, 0, stream>>>(c2_W3, W3T);
  w2t_kernel<<<8, 256, 0, stream>>>(c2_W2, W2T);
  sumcols128_kernel<<<64, 256, 0, stream>>>(partialP, 128, mid);
  stats_final_kernel<<<1, 256, 0, stream>>>(mid, 64, 64, invPK, c2_g1, c2_be1, ssA);
  conv2_l2_mfma<<<PK/128, 256, 0, stream>>>(bufA, ssA, W2T, c2_b2, zhb, partialB);
  sumcols256_kernel<<<64, 256, 0, stream>>>(partialB, midB);
  stats_final_kernel<<<1, 256, 0, stream>>>(midB, 64, 128, invPK, c2_g2, c2_be2, ssB);
  conv2_l3max_mfma<<<PK/64, 256, 0, stream>>>(zhb, ssB, W3T, c2_b3, bufA);
  pool1_kernel<<<NB*64, 256, 0, stream>>>(bufA, pmax);
  pool2_kernel<<<PTS/256, 256, 0, stream>>>(pmax, gpool);
  lin_kernel<<<32, 256, 0, stream>>>(gpool, lin_W, zpart);
  final_kernel<<<1, 256, 0, stream>>>(zpart, lin_b, lin_g, lin_be, out);
}